// Round 12
// baseline (1319.653 us; speedup 1.0000x reference)
//
#include <hip/hip_runtime.h>
#include <hip/hip_bf16.h>
#include <float.h>

// Problem constants (from reference setup_inputs)
#define B_   4
#define N_   4096
#define J_   24
#define KR_  4
#define KNN_ 20
#define SLOPE 0.2f
#define SLABN 64             // points per pooling slab
#define NSLAB (N_ / SLABN)   // 64
#define SCAPW 320            // per-wave survivor cap for k_selC3
#define FS_CAP 160           // per-row survivor cap in fused dist+sel
#define KSLACK 8u            // u16-key slack covering split-bf16 error

typedef __attribute__((ext_vector_type(8))) short bf16x8;
typedef __attribute__((ext_vector_type(4))) float f32x4;

// ---------- per-point squared norm ----------
__global__ void k_norm(const float* __restrict__ h, float* __restrict__ xx, int C) {
    int i = blockIdx.x * blockDim.x + threadIdx.x;
    if (i >= B_ * N_) return;
    const float* hp = h + (size_t)i * C;
    float s = 0.f;
    for (int c = 0; c < C; ++c) { float v = hp[c]; s += v * v; }
    xx[i] = s;
}

// ---------- monotone key maps ----------
__device__ __forceinline__ unsigned mapf(float f) {
    unsigned u = __float_as_uint(f);
    return (u & 0x80000000u) ? ~u : (u | 0x80000000u);
}
// top-16 bits of mapf: monotone f32 -> u16 (truncation preserves order)
__device__ __forceinline__ unsigned key16(float f) {
    return mapf(f) >> 16;
}

// ---------- split f32 -> bf16 hi + bf16 lo (both truncated) ----------
__global__ void k_split(const float* __restrict__ h, unsigned short* __restrict__ hi,
                        unsigned short* __restrict__ lo, int total4) {
    int i = blockIdx.x * 256 + threadIdx.x;
    if (i >= total4) return;
    float4 v = ((const float4*)h)[i];
    ushort4 h4, l4;
    {
        unsigned u = __float_as_uint(v.x); h4.x = (unsigned short)(u >> 16);
        float r = v.x - __uint_as_float(u & 0xffff0000u); l4.x = (unsigned short)(__float_as_uint(r) >> 16);
    }
    {
        unsigned u = __float_as_uint(v.y); h4.y = (unsigned short)(u >> 16);
        float r = v.y - __uint_as_float(u & 0xffff0000u); l4.y = (unsigned short)(__float_as_uint(r) >> 16);
    }
    {
        unsigned u = __float_as_uint(v.z); h4.z = (unsigned short)(u >> 16);
        float r = v.z - __uint_as_float(u & 0xffff0000u); l4.z = (unsigned short)(__float_as_uint(r) >> 16);
    }
    {
        unsigned u = __float_as_uint(v.w); h4.w = (unsigned short)(u >> 16);
        float r = v.w - __uint_as_float(u & 0xffff0000u); l4.w = (unsigned short)(__float_as_uint(r) >> 16);
    }
    ((ushort4*)hi)[i] = h4;
    ((ushort4*)lo)[i] = l4;
}

// ---------- ballot-based wave radix select ----------
// r-th smallest (1-indexed) of the 64 lanes' values, low nbits significant.
__device__ __forceinline__ unsigned radixsel_wave(unsigned val, int r, int nbits) {
    unsigned long long cand = ~0ull;
    unsigned prefix = 0;
    for (int bit = nbits - 1; bit >= 0; --bit) {
        unsigned long long z = cand & __ballot(!((val >> bit) & 1u));
        int cz = __popcll(z);
        if (cz >= r) cand = z;
        else { r -= cz; cand &= ~z; prefix |= 1u << bit; }
    }
    return prefix;
}

// exact r-th smallest of S u16 keys in LDS (lane handles idx lane, lane+64, lane+128)
__device__ __forceinline__ unsigned radixsel_multi16(const unsigned short* keys,
                                                     int S, int lane, int r) {
    unsigned k0 = 0, k1 = 0, k2 = 0;
    unsigned act = 0;
    if (lane < S)        { k0 = keys[lane];        act |= 1u; }
    if (lane + 64 < S)   { k1 = keys[lane + 64];   act |= 2u; }
    if (lane + 128 < S)  { k2 = keys[lane + 128];  act |= 4u; }
    unsigned prefix = 0;
    for (int bit = 15; bit >= 0; --bit) {
        unsigned zm = 0; int c = 0;
        if ((act & 1u) && !((k0 >> bit) & 1u)) { zm |= 1u; ++c; }
        if ((act & 2u) && !((k1 >> bit) & 1u)) { zm |= 2u; ++c; }
        if ((act & 4u) && !((k2 >> bit) & 1u)) { zm |= 4u; ++c; }
        unsigned long long b0 = __ballot(c >= 1);
        unsigned long long b1 = __ballot(c >= 2);
        unsigned long long b2 = __ballot(c >= 3);
        int tot = __popcll(b0) + __popcll(b1) + __popcll(b2);
        if (tot >= r) act = zm;
        else { r -= tot; act &= ~zm; prefix |= 1u << bit; }
    }
    return prefix;
}

// Given per-lane u64 key (hi = mapf(d), lo = idx) and active flag: is this lane
// among the 20 smallest active keys? Exact, tie-stable. Pure ballot/popcount.
__device__ __forceinline__ bool top20_round(unsigned long long key, bool active) {
    unsigned hi = (unsigned)(key >> 32);
    unsigned lo = (unsigned)key;
    unsigned long long amask = __ballot(active);
    int navail = __popcll(amask);
    if (navail <= KNN_) return active;
    int r = KNN_;
    unsigned long long cand = amask;
    unsigned prefix = 0;
    for (int bit = 31; bit >= 0; --bit) {
        unsigned long long z = cand & __ballot(!((hi >> bit) & 1u));
        int cz = __popcll(z);
        if (cz >= r) cand = z;
        else { r -= cz; cand &= ~z; prefix |= 1u << bit; }
    }
    unsigned long long c2 = __ballot(active && hi == prefix);
    unsigned p2 = 0;
    for (int bit = 11; bit >= 0; --bit) {
        unsigned long long z = c2 & __ballot(!((lo >> bit) & 1u));
        int cz = __popcll(z);
        if (cz >= r) c2 = z;
        else { r -= cz; c2 &= ~z; p2 |= 1u << bit; }
    }
    return active && (hi < prefix || (hi == prefix && lo <= p2));
}

// Per-wave exact top-20 of skey[0..S); winners ordered via all-pairs rank.
__device__ __forceinline__ void final_top20(const unsigned long long* skey, int S,
                                            unsigned long long* wbuf,
                                            int lane, int* idxout, int obase) {
    unsigned long long key = (lane < S) ? skey[lane] : ~0ull;
    bool active = (lane < S);
    int consumed = (S < 64) ? S : 64;
    int nw = 0;
    for (;;) {
        bool win = top20_round(key, active);
        unsigned long long wb = __ballot(win);
        nw = __popcll(wb);
        int pos = __popcll(wb & ((1ull << lane) - 1ull));
        if (win) wbuf[pos] = key;
        if (consumed >= S) break;
        int src = consumed + lane - nw;
        key = (lane < nw) ? wbuf[lane] : ((src < S) ? skey[src] : ~0ull);
        active = (lane < nw) || (src >= consumed && src < S);
        consumed += 64 - nw;
    }
    if (lane < nw) {
        unsigned long long mine = wbuf[lane];
        int rank = 0;
        for (int i = 0; i < nw; ++i) rank += (wbuf[i] < mine);
        idxout[obase + rank] = (int)(unsigned)mine;
    }
}

// ---------- FUSED distance + top-20 selection (XCD-batch-affine) ----------
// 1D grid, batch-major logical blocks. HW round-robins blockIdx across the 8
// XCDs, so swz = (bid&7)*cpx + (bid>>3) gives each XCD a CONTIGUOUS logical
// chunk; with logical = batch-major, each XCD hosts exactly one batch's
// blocks -> that batch's X (<=2 MB bf16-split) stays resident in the XCD's
// 4 MB L2 (previous version thrashed: all 4 batches per XCD, FETCH 128 MB).
// Selection machinery identical to round 10 (proofs unchanged).
__global__ __launch_bounds__(256) void k_distsel(const unsigned short* __restrict__ Hi,
                                                 const unsigned short* __restrict__ Lo,
                                                 int C,
                                                 const float* __restrict__ Xall,
                                                 const float* __restrict__ xxall,
                                                 int* __restrict__ knnIdx) {
    __shared__ unsigned short tile[64][256];        // 32 KB, group-swizzled
    __shared__ unsigned short kbuf[64][FS_CAP];     // 20 KB survivor u16 keys
    __shared__ unsigned short cbuf[64][FS_CAP];     // 20 KB survivor cols
    __shared__ unsigned long long skey2[4][FS_CAP]; // 5 KB final scratch
    __shared__ unsigned long long wbuf[4][24];
    __shared__ unsigned tauA[64];
    __shared__ int scntA[64];

    int nwg = gridDim.x;                  // 256 (divisible by 8 -> bijective)
    int cpx = nwg >> 3;
    int bid = blockIdx.x;
    int swz = (bid & 7) * cpx + (bid >> 3);
    int b  = swz >> 6;                    // batch (batch-major logical order)
    int R0 = (swz & 63) << 6;             // row group

    const unsigned short* XH = Hi + (size_t)b * N_ * C;
    const unsigned short* XL = Lo + (size_t)b * N_ * C;
    const float* Xb  = Xall + (size_t)b * N_ * C;
    const float* xxb = xxall + (size_t)b * N_;
    int* idxout = knnIdx + (size_t)b * N_ * KNN_;
    int tid = threadIdx.x, wv = tid >> 6, lane = tid & 63;
    int lp = lane & 15, kgrp = lane >> 4, rsub = (lane >> 4) * 4;
    int cwoff = wv * 64;
    unsigned long long lmaskLT = (1ull << lane) - 1ull;

    float xxrv = xxb[R0 + lane];

    for (int it = 0; it < 16; ++it) {
        int cb0 = it * 256 + cwoff;
        // ---- MFMA: 64x64 quadrant for this wave ----
        f32x4 acc[4][4];
#pragma unroll
        for (int i = 0; i < 4; ++i)
#pragma unroll
            for (int j = 0; j < 4; ++j) acc[i][j] = (f32x4){0.f, 0.f, 0.f, 0.f};
        for (int ks = 0; ks < C; ks += 32) {
            int kb = ks + kgrp * 8;
            bf16x8 ah[4], al[4];
#pragma unroll
            for (int fi = 0; fi < 4; ++fi) {
                size_t ro = (size_t)(R0 + fi * 16 + lp) * C + kb;
                ah[fi] = *(const bf16x8*)(XH + ro);
                al[fi] = *(const bf16x8*)(XL + ro);
            }
#pragma unroll
            for (int fj = 0; fj < 4; ++fj) {
                size_t co = (size_t)(cb0 + fj * 16 + lp) * C + kb;
                bf16x8 bh = *(const bf16x8*)(XH + co);
                bf16x8 bl = *(const bf16x8*)(XL + co);
#pragma unroll
                for (int fi = 0; fi < 4; ++fi) {
                    acc[fi][fj] = __builtin_amdgcn_mfma_f32_16x16x32_bf16(ah[fi], bh, acc[fi][fj], 0, 0, 0);
                    acc[fi][fj] = __builtin_amdgcn_mfma_f32_16x16x32_bf16(ah[fi], bl, acc[fi][fj], 0, 0, 0);
                    acc[fi][fj] = __builtin_amdgcn_mfma_f32_16x16x32_bf16(al[fi], bh, acc[fi][fj], 0, 0, 0);
                }
            }
        }
        // ---- epilogue: keys into swizzled LDS tile ----
        float xxcv = xxb[cb0 + lane];
#pragma unroll
        for (int fi = 0; fi < 4; ++fi) {
#pragma unroll
            for (int fj = 0; fj < 4; ++fj) {
                float xc = __shfl(xxcv, fj * 16 + lp, 64);
#pragma unroll
                for (int r = 0; r < 4; ++r) {
                    float xr = __shfl(xxrv, fi * 16 + rsub + r, 64);
                    float d = xr + xc - 2.f * acc[fi][fj][r];
                    int row = fi * 16 + rsub + r;
                    int col = cwoff + fj * 16 + lp;
                    int pg = (col >> 3) ^ ((row >> 2) & 31);
                    tile[row][(pg << 3) | (col & 7)] = (unsigned short)key16(d);
                }
            }
        }
        __syncthreads();
        // ---- selection: this wave streams its 16 rows ----
        for (int rr = 0; rr < 16; ++rr) {
            int row = (wv << 4) + rr;
            int pg = (lane >> 1) ^ ((row >> 2) & 31);
            const unsigned* kp = (const unsigned*)&tile[row][(pg << 3) | ((lane & 1) << 2)];
            unsigned w0 = kp[0], w1 = kp[1];
            unsigned k4[4];
            k4[0] = w0 & 0xffffu; k4[1] = w0 >> 16;
            k4[2] = w1 & 0xffffu; k4[3] = w1 >> 16;
            unsigned mn4 = k4[0];
            mn4 = (k4[1] < mn4) ? k4[1] : mn4;
            mn4 = (k4[2] < mn4) ? k4[2] : mn4;
            mn4 = (k4[3] < mn4) ? k4[3] : mn4;

            unsigned tau;
            int scnt = 0;
            bool doApp;
            if (it == 0) {
                tau = radixsel_wave(mn4, KNN_, 16) + KSLACK;
                if (tau > 0xffffu) tau = 0xffffu;
                doApp = true;
            } else {
                tau = tauA[row];
                doApp = (__ballot(mn4 <= tau) != 0ull);
                if (doApp) scnt = scntA[row];
            }
            if (doApp) {
                int gc = it * 256 + (lane << 2);
#pragma unroll
                for (int t = 0; t < 4; ++t) {
                    bool in = (k4[t] <= tau);
                    unsigned long long m = __ballot(in);
                    int pos = scnt + __popcll(m & lmaskLT);
                    if (in && pos < FS_CAP) {
                        kbuf[row][pos] = (unsigned short)k4[t];
                        cbuf[row][pos] = (unsigned short)(gc + t);
                    }
                    scnt += __popcll(m);
                }
                if (scnt > FS_CAP) scnt = FS_CAP;
                if (lane == 0) {
                    scntA[row] = scnt;
                    if (it == 0) tauA[row] = tau;
                }
            }
            if (it == 2 || it == 7) {
                // tighten: exact 20th of survivor keys (+KSLACK), compact
                int S = scntA[row];
                unsigned t2 = radixsel_multi16(&kbuf[row][0], S, lane, KNN_) + KSLACK;
                if (t2 > 0xffffu) t2 = 0xffffu;
                int S2 = 0;
                for (int base = 0; base < S; base += 64) {
                    int si = base + lane;
                    unsigned kk = 0, cc = 0; bool in = false;
                    if (si < S) {
                        kk = kbuf[row][si]; cc = cbuf[row][si];
                        in = (kk <= t2);
                    }
                    unsigned long long m = __ballot(in);
                    int pos = S2 + __popcll(m & lmaskLT);
                    if (in) {
                        kbuf[row][pos] = (unsigned short)kk;
                        cbuf[row][pos] = (unsigned short)cc;
                    }
                    S2 += __popcll(m);
                }
                if (lane == 0) { scntA[row] = S2; tauA[row] = t2; }
            }
        }
        __syncthreads();
    }

    // ---- final: exact recompute + exact tie-stable top-20 per row ----
    for (int rr = 0; rr < 16; ++rr) {
        int row = (wv << 4) + rr;
        int grow = R0 + row;
        int S = scntA[row]; if (S > FS_CAP) S = FS_CAP;
        float xxq = xxb[grow];
        const float4* xq4 = (const float4*)(Xb + (size_t)grow * C);
        unsigned myk[3] = {0xffffffffu, 0xffffffffu, 0xffffffffu};
        unsigned myc[3] = {0u, 0u, 0u};
        unsigned mn = 0xffffffffu;
#pragma unroll
        for (int ch = 0; ch < 3; ++ch) {
            int s = lane + (ch << 6);
            if (s < S) {
                int j = (int)cbuf[row][s];
                const float4* xj = (const float4*)(Xb + (size_t)j * C);
                float a0 = 0.f, a1 = 0.f, a2 = 0.f, a3 = 0.f;
                for (int c4 = 0; c4 < (C >> 2); ++c4) {
                    float4 x = xj[c4]; float4 qv = xq4[c4];
                    a0 = fmaf(qv.x, x.x, a0);
                    a1 = fmaf(qv.y, x.y, a1);
                    a2 = fmaf(qv.z, x.z, a2);
                    a3 = fmaf(qv.w, x.w, a3);
                }
                float d = xxq + xxb[j] - 2.f * ((a0 + a1) + (a2 + a3));
                unsigned k = mapf(d);
                myk[ch] = k; myc[ch] = (unsigned)j;
                mn = (k < mn) ? k : mn;
            }
        }
        unsigned tau3 = radixsel_wave(mn, KNN_, 32);
        int nch = (S + 63) >> 6;
        int S2 = 0;
#pragma unroll
        for (int ch = 0; ch < 3; ++ch) {
            if (ch >= nch) break;                      // uniform
            bool in = (lane + (ch << 6) < S) && (myk[ch] <= tau3);
            unsigned long long m = __ballot(in);
            int pos = S2 + __popcll(m & lmaskLT);
            if (in) skey2[wv][pos] = ((unsigned long long)myk[ch] << 32) | myc[ch];
            S2 += __popcll(m);
        }
        final_top20(skey2[wv], S2, wbuf[wv], lane, idxout, grow * KNN_);
    }
}

// ---------- layer-1 wave-autonomous dist+select (C=3), exact f32 keys ----------
__global__ __launch_bounds__(256) void k_selC3(const float* __restrict__ V,
                                               const float* __restrict__ xx,
                                               int* __restrict__ knnIdx) {
    __shared__ unsigned long long skey[4][SCAPW];
    __shared__ unsigned long long wbuf[4][24];
    __shared__ int scnt[4];
    int b    = blockIdx.y;
    const float* Xb  = V + (size_t)b * N_ * 3;
    const float* xxb = xx + (size_t)b * N_;
    int* idxout = knnIdx + (size_t)b * N_ * KNN_;
    int wv   = threadIdx.x >> 6;
    int lane = threadIdx.x & 63;
    int q    = blockIdx.x * 4 + wv;
    if (lane == 0) scnt[wv] = 0;

    float qx = Xb[q * 3], qy = Xb[q * 3 + 1], qz = Xb[q * 3 + 2];
    float xxq = xxb[q];

    unsigned kk[64];
#pragma unroll
    for (int cq = 0; cq < 4; ++cq) {
        int jb = (cq * 64 + lane) * 16;
        float pts[48];
        const float4* src = (const float4*)(Xb + (size_t)jb * 3);
#pragma unroll
        for (int t = 0; t < 12; ++t) ((float4*)pts)[t] = src[t];
#pragma unroll
        for (int t = 0; t < 16; ++t) {
            float dot = qx * pts[3 * t];
            dot = fmaf(qy, pts[3 * t + 1], dot);
            dot = fmaf(qz, pts[3 * t + 2], dot);
            float d = xxq + xxb[jb + t] - 2.f * dot;
            kk[cq * 16 + t] = mapf(d);
        }
    }

    unsigned mn = kk[0];
#pragma unroll
    for (int t = 1; t < 64; ++t) mn = (kk[t] < mn) ? kk[t] : mn;
    unsigned tau = radixsel_wave(mn, KNN_, 32);   // exact keys: no slack needed

    int nl = 0;
#pragma unroll
    for (int t = 0; t < 64; ++t) nl += (kk[t] <= tau);
    int p = atomicAdd(&scnt[wv], nl);
#pragma unroll
    for (int cq = 0; cq < 4; ++cq) {
        int jb = (cq * 64 + lane) * 16;
#pragma unroll
        for (int t = 0; t < 16; ++t) {
            if (kk[cq * 16 + t] <= tau) {
                if (p < SCAPW)
                    skey[wv][p] = ((unsigned long long)kk[cq * 16 + t] << 32) | (unsigned)(jb + t);
                ++p;
            }
        }
    }
    int S = scnt[wv];
    if (S > SCAPW) S = SCAPW;
    final_top20(skey[wv], S, wbuf[wv], lane, idxout, q * KNN_);
}

// ---------- fused weight prep ----------
__device__ __forceinline__ void prepP_elem(const float* __restrict__ w,
                                           const float* __restrict__ bias,
                                           int C, int O, float* __restrict__ P,
                                           float* __restrict__ b2, int i) {
    int O2 = 2 * O;
    if (i < O2) b2[i] = (i < O) ? 0.f : bias[i - O];
    if (i >= C * O2) return;
    int k = i / O2, col = i % O2;
    float v;
    if (col < O) v = w[(size_t)col * 2 * C + k];
    else { int o = col - O; v = w[(size_t)o * 2 * C + C + k] - w[(size_t)o * 2 * C + k]; }
    P[i] = v;
}
__device__ __forceinline__ void transp_elem(const float* __restrict__ w, int O, int K,
                                            float* __restrict__ wT, int i) {
    if (i >= O * K) return;
    int k = i / O, o = i % O;
    wT[i] = w[(size_t)o * K + k];
}

__global__ void k_prepall(const float* g1w, const float* g1b,
                          const float* g2w, const float* g2b,
                          const float* g3w, const float* g3b,
                          const float* s1w, const float* s1b,
                          const float* s2w, const float* s2b,
                          const float* s3w, const float* s3b,
                          const float* m1w, const float* m2w, const float* m3w,
                          float* P1, float* P2, float* P3, float* P4, float* P5,
                          float* P6, float* P7, float* P8, float* P9,
                          float* bb1, float* bb2, float* bb3,
                          float* bb4, float* bb5, float* bb6) {
    int i = blockIdx.x * 256 + threadIdx.x;
    switch (blockIdx.y) {
        case 0: prepP_elem(g1w, g1b, 3,   64,  P1, bb1, i); break;
        case 1: prepP_elem(g2w, g2b, 64,  128, P2, bb2, i); break;
        case 2: prepP_elem(g3w, g3b, 128, 256, P3, bb3, i); break;
        case 3: prepP_elem(s1w, s1b, 451, 256, P4, bb4, i); break;
        case 4: prepP_elem(s2w, s2b, 256, 128, P5, bb5, i); break;
        case 5: prepP_elem(s3w, s3b, 128, 64,  P6, bb6, i); break;
        case 6: transp_elem(m1w, 512, 448, P7, i); break;
        case 7: transp_elem(m2w, 256, 512, P8, i); break;
        case 8: transp_elem(m3w, 3,   256, P9, i); break;
    }
}

// ---------- tiled f32 GEMM (large M) ----------
__global__ __launch_bounds__(256) void k_gemm(const float* __restrict__ A, int lda,
                                              const float* __restrict__ Bm,
                                              float* __restrict__ Cm, int ldc,
                                              int M, int N, int K,
                                              const float* __restrict__ bias, int leaky) {
    __shared__ float As[16][68];
    __shared__ float Bs[16][68];
    int tid = threadIdx.x;
    int row0 = blockIdx.y * 64, col0 = blockIdx.x * 64;
    int tr = tid >> 4, tc = tid & 15;
    float acc[4][4] = {{0.f}};
    for (int kt = 0; kt < K; kt += 16) {
#pragma unroll
        for (int i = 0; i < 4; ++i) {
            int e = tid + 256 * i;
            int r = e >> 4, kk = e & 15;
            int gr = row0 + r, gk = kt + kk;
            float v = 0.f;
            if (gr < M && gk < K) v = A[(size_t)gr * lda + gk];
            As[kk][r] = v;
        }
#pragma unroll
        for (int i = 0; i < 4; ++i) {
            int e = tid + 256 * i;
            int kk = e >> 6, c = e & 63;
            int gk = kt + kk, gc = col0 + c;
            float v = 0.f;
            if (gk < K && gc < N) v = Bm[(size_t)gk * N + gc];
            Bs[kk][c] = v;
        }
        __syncthreads();
#pragma unroll
        for (int kk = 0; kk < 16; ++kk) {
            float a[4], bv[4];
            *(float4*)&a[0]  = *(const float4*)&As[kk][tr * 4];
            *(float4*)&bv[0] = *(const float4*)&Bs[kk][tc * 4];
#pragma unroll
            for (int i = 0; i < 4; ++i)
#pragma unroll
                for (int j = 0; j < 4; ++j) acc[i][j] += a[i] * bv[j];
        }
        __syncthreads();
    }
#pragma unroll
    for (int i = 0; i < 4; ++i) {
        int r = row0 + tr * 4 + i;
        if (r >= M) continue;
#pragma unroll
        for (int j = 0; j < 4; ++j) {
            int c = col0 + tc * 4 + j;
            if (c >= N) continue;
            float v = acc[i][j];
            if (bias) v += bias[c];
            if (leaky) v = v >= 0.f ? v : SLOPE * v;
            Cm[(size_t)r * ldc + c] = v;
        }
    }
}

// ---------- small-M GEMM ----------
__global__ __launch_bounds__(256) void k_sgemm(const float* __restrict__ A, int lda,
                                               const float* __restrict__ Bm,
                                               float* __restrict__ Cm, int ldc,
                                               int N, int K,
                                               const float* __restrict__ bias, int leaky) {
    extern __shared__ float Arow[];
    int r   = blockIdx.x;
    int c0  = blockIdx.y * 256;
    int tid = threadIdx.x;
    for (int k = tid; k < K; k += 256) Arow[k] = A[(size_t)r * lda + k];
    __syncthreads();
    int c = c0 + tid;
    if (c >= N) return;
    float acc = bias ? bias[c] : 0.f;
    for (int k = 0; k < K; ++k) acc += Arow[k] * Bm[(size_t)k * N + c];
    if (leaky) acc = acc >= 0.f ? acc : SLOPE * acc;
    Cm[(size_t)r * ldc + c] = acc;
}

// ---------- gather-max epilogue (+ optional fused row-norm) ----------
__global__ void k_gathermax(const float* __restrict__ Y, int O, int R,
                            const int* __restrict__ idx, int kc,
                            float* __restrict__ out, int ldo, int ooff,
                            float* __restrict__ xxout) {
    extern __shared__ int sidx[];
    __shared__ float red[256];
    int br = blockIdx.x;
    int b  = br / R;
    int o  = threadIdx.x;
    if (o < kc) sidx[o] = idx[(size_t)br * kc + o];
    __syncthreads();
    int O2 = 2 * O;
    float z = Y[(size_t)br * O2 + O + o];
    float best = -FLT_MAX;
    for (int k = 0; k < kc; ++k) {
        int m = sidx[k];
        best = fmaxf(best, Y[(size_t)(b * R + m) * O2 + o]);
    }
    float r = z + best;
    r = r >= 0.f ? r : SLOPE * r;
    out[(size_t)br * ldo + ooff + o] = r;
    if (xxout) {
        red[o] = r * r;
        __syncthreads();
        for (int s = blockDim.x >> 1; s > 0; s >>= 1) {
            if (o < s) red[o] += red[o + s];
            __syncthreads();
        }
        if (o == 0) xxout[br] = red[0];
    }
}

// ---------- channel map ----------
__device__ __forceinline__ void chan_map(int b, int c,
                                         const float* Vf, const float* l1,
                                         const float* l2, const float* l3,
                                         const float*& p, int& st) {
    if (c < 3)        { st = 3;   p = Vf + (size_t)b * N_ * 3   + c; }
    else if (c < 67)  { st = 64;  p = l1 + (size_t)b * N_ * 64  + (c - 3); }
    else if (c < 195) { st = 128; p = l2 + (size_t)b * N_ * 128 + (c - 67); }
    else              { st = 256; p = l3 + (size_t)b * N_ * 256 + (c - 195); }
}

// ---------- pooling phase 1 ----------
__global__ __launch_bounds__(256) void k_pool2(const float* __restrict__ Vf,
                                               const float* __restrict__ l1,
                                               const float* __restrict__ l2,
                                               const float* __restrict__ l3,
                                               const float* __restrict__ W,
                                               float* __restrict__ ppool,
                                               float* __restrict__ psw) {
    __shared__ float Wl[SLABN][J_];
    int blk  = blockIdx.x;
    int b    = blk / NSLAB, slab = blk % NSLAB;
    int n0   = slab * SLABN;
    int tid  = threadIdx.x;

    for (int e = tid; e < J_ * SLABN; e += 256) {
        int j = e / SLABN, n = e % SLABN;
        Wl[n][j] = W[((size_t)b * J_ + j) * N_ + n0 + n];
    }
    __syncthreads();

    if (tid < J_) {
        float s = 0.f;
        for (int n = 0; n < SLABN; ++n) s += Wl[n][tid];
        psw[(size_t)blk * J_ + tid] = s;
    }

    int c0 = tid, c1 = tid + 256;
    const float *p0, *p1 = nullptr; int s0, s1 = 0;
    chan_map(b, c0, Vf, l1, l2, l3, p0, s0);
    bool has1 = (c1 < 451);
    if (has1) chan_map(b, c1, Vf, l1, l2, l3, p1, s1);

    float acc0[J_], acc1[J_];
#pragma unroll
    for (int j = 0; j < J_; ++j) { acc0[j] = 0.f; acc1[j] = 0.f; }

    for (int n = 0; n < SLABN; ++n) {
        float v0 = p0[(size_t)(n0 + n) * s0];
        float v1 = has1 ? p1[(size_t)(n0 + n) * s1] : 0.f;
        const float* wn = &Wl[n][0];
#pragma unroll
        for (int q = 0; q < J_ / 4; ++q) {
            float4 w4 = *(const float4*)(wn + 4 * q);
            acc0[4*q+0] += w4.x * v0;  acc1[4*q+0] += w4.x * v1;
            acc0[4*q+1] += w4.y * v0;  acc1[4*q+1] += w4.y * v1;
            acc0[4*q+2] += w4.z * v0;  acc1[4*q+2] += w4.z * v1;
            acc0[4*q+3] += w4.w * v0;  acc1[4*q+3] += w4.w * v1;
        }
    }
    float* pp = ppool + (size_t)blk * J_ * 451;
#pragma unroll
    for (int j = 0; j < J_; ++j) {
        pp[(size_t)j * 451 + c0] = acc0[j];
        if (has1) pp[(size_t)j * 451 + c1] = acc1[j];
    }
}

// ---------- pooling phase 2 ----------
__global__ __launch_bounds__(256) void k_poolred(const float* __restrict__ ppool,
                                                 const float* __restrict__ psw,
                                                 float* __restrict__ pooled) {
    int bj = blockIdx.x;
    int b  = bj / J_, j = bj % J_;
    int tid = threadIdx.x;

    float sw = 0.f;
    for (int sl = 0; sl < NSLAB; ++sl) sw += psw[(size_t)(b * NSLAB + sl) * J_ + j];
    float inv = 1.f / (sw + 1e-5f);

    for (int c = tid; c < 451; c += 256) {
        float s = 0.f;
        for (int sl = 0; sl < NSLAB; ++sl)
            s += ppool[((size_t)(b * NSLAB + sl) * J_ + j) * 451 + c];
        pooled[(size_t)bj * 451 + c] = s * inv;
    }
}

extern "C" void kernel_launch(void* const* d_in, const int* in_sizes, int n_in,
                              void* d_out, int out_size, void* d_ws, size_t ws_size,
                              hipStream_t stream) {
    const float* V  = (const float*)d_in[0];
    const float* W  = (const float*)d_in[1];
    const int* ringIdx = (const int*)d_in[2];
    const float* g1w = (const float*)d_in[3];
    const float* g1b = (const float*)d_in[4];
    const float* g2w = (const float*)d_in[5];
    const float* g2b = (const float*)d_in[6];
    const float* g3w = (const float*)d_in[7];
    const float* g3b = (const float*)d_in[8];
    const float* s1w = (const float*)d_in[9];
    const float* s1b = (const float*)d_in[10];
    const float* s2w = (const float*)d_in[11];
    const float* s2b = (const float*)d_in[12];
    const float* s3w = (const float*)d_in[13];
    const float* s3b = (const float*)d_in[14];
    const float* m1w = (const float*)d_in[15];
    const float* m1b = (const float*)d_in[16];
    const float* m2w = (const float*)d_in[17];
    const float* m2b = (const float*)d_in[18];
    const float* m3w = (const float*)d_in[19];
    const float* m3b = (const float*)d_in[20];
    (void)n_in; (void)in_sizes; (void)out_size; (void)ws_size;

    const int szP1 = 3 * 128,    szP2 = 64 * 256,  szP3 = 128 * 512;
    const int szP4 = 451 * 512,  szP5 = 256 * 256, szP6 = 128 * 128;
    const int szP7 = 448 * 512,  szP8 = 512 * 256, szP9 = 256 * 3;

    // Y/pool region (floats): Y (M*512) and the pooling scratch alias it.
    size_t ymax = (size_t)B_ * N_ * 512;
    size_t pool = (size_t)B_ * NSLAB * J_ * 451 + (size_t)B_ * NSLAB * J_;
    size_t dreg = (ymax > pool) ? ymax : pool;

    // ---- workspace layout (floats) ----
    float* ws = (float*)d_ws;
    size_t off = 0;
    float* l1 = ws + off; off += (size_t)B_ * N_ * 64;
    float* l2 = ws + off; off += (size_t)B_ * N_ * 128;
    float* l3 = ws + off; off += (size_t)B_ * N_ * 256;
    float* xx = ws + off; off += (size_t)B_ * N_;
    float* Y  = ws + off; off += dreg;
    float* ppool = Y;
    float* psw   = Y + (size_t)B_ * NSLAB * J_ * 451;
    unsigned short* Xhi = (unsigned short*)(ws + off); off += (size_t)B_ * N_ * 128 / 2;
    unsigned short* Xlo = (unsigned short*)(ws + off); off += (size_t)B_ * N_ * 128 / 2;
    int* knnIdx = (int*)(ws + off); off += (size_t)B_ * N_ * KNN_;
    float* pooled = ws + off; off += (size_t)B_ * J_ * 451;
    float* joints = ws + off; off += (size_t)B_ * J_ * 448;
    float* h1 = ws + off; off += (size_t)B_ * J_ * 512;
    float* h2 = ws + off; off += (size_t)B_ * J_ * 256;
    float* P1 = ws + off; off += szP1;
    float* P2 = ws + off; off += szP2;
    float* P3 = ws + off; off += szP3;
    float* P4 = ws + off; off += szP4;
    float* P5 = ws + off; off += szP5;
    float* P6 = ws + off; off += szP6;
    float* P7 = ws + off; off += szP7;
    float* P8 = ws + off; off += szP8;
    float* P9 = ws + off; off += szP9;
    float* bb1 = ws + off; off += 128;
    float* bb2 = ws + off; off += 256;
    float* bb3 = ws + off; off += 512;
    float* bb4 = ws + off; off += 512;
    float* bb5 = ws + off; off += 256;
    float* bb6 = ws + off; off += 128;

    const int M = B_ * N_;   // 16384
    const int MJ = B_ * J_;  // 96

    // ---- all weight prep in one launch ----
    k_prepall<<<dim3((szP4 + 255) / 256, 9), 256, 0, stream>>>(
        g1w, g1b, g2w, g2b, g3w, g3b, s1w, s1b, s2w, s2b, s3w, s3b,
        m1w, m2w, m3w, P1, P2, P3, P4, P5, P6, P7, P8, P9,
        bb1, bb2, bb3, bb4, bb5, bb6);

    // ======== geoNet layer 1: C=3 -> O=64 (fused dist+select) ========
    k_norm<<<(M + 255) / 256, 256, 0, stream>>>(V, xx, 3);
    k_selC3<<<dim3(N_ / 4, B_), 256, 0, stream>>>(V, xx, knnIdx);
    k_gemm<<<dim3(2, M / 64), 256, 0, stream>>>(V, 3, P1, Y, 128, M, 128, 3, bb1, 0);
    k_gathermax<<<M, 64, KNN_ * sizeof(int), stream>>>(Y, 64, N_, knnIdx, KNN_, l1, 64, 0, xx);

    // ======== layer 2: C=64 -> O=128 (fused dist+select, XCD-affine) ========
    k_split<<<(M * 64 / 4 + 255) / 256, 256, 0, stream>>>(l1, Xhi, Xlo, M * 64 / 4);
    k_distsel<<<dim3((N_ / 64) * B_), 256, 0, stream>>>(Xhi, Xlo, 64, l1, xx, knnIdx);
    k_gemm<<<dim3(4, M / 64), 256, 0, stream>>>(l1, 64, P2, Y, 256, M, 256, 64, bb2, 0);
    k_gathermax<<<M, 128, KNN_ * sizeof(int), stream>>>(Y, 128, N_, knnIdx, KNN_, l2, 128, 0, xx);

    // ======== layer 3: C=128 -> O=256 (fused dist+select, XCD-affine) ========
    k_split<<<(M * 128 / 4 + 255) / 256, 256, 0, stream>>>(l2, Xhi, Xlo, M * 128 / 4);
    k_distsel<<<dim3((N_ / 64) * B_), 256, 0, stream>>>(Xhi, Xlo, 128, l2, xx, knnIdx);
    k_gemm<<<dim3(8, M / 64), 256, 0, stream>>>(l2, 128, P3, Y, 512, M, 512, 128, bb3, 0);
    k_gathermax<<<M, 256, KNN_ * sizeof(int), stream>>>(Y, 256, N_, knnIdx, KNN_, l3, 256, 0, nullptr);

    // ======== pooling onto joints ========
    k_pool2<<<B_ * NSLAB, 256, 0, stream>>>(V, l1, l2, l3, W, ppool, psw);
    k_poolred<<<MJ, 256, 0, stream>>>(ppool, psw, pooled);

    // ======== skeleton convs ========
    k_sgemm<<<dim3(MJ, 2), 256, 451 * sizeof(float), stream>>>(pooled, 451, P4, Y, 512, 512, 451, bb4, 0);
    k_gathermax<<<MJ, 256, KR_ * sizeof(int), stream>>>(Y, 256, J_, ringIdx, KR_, joints, 448, 0, nullptr);

    k_sgemm<<<dim3(MJ, 1), 256, 256 * sizeof(float), stream>>>(joints, 448, P5, Y, 256, 256, 256, bb5, 0);
    k_gathermax<<<MJ, 128, KR_ * sizeof(int), stream>>>(Y, 128, J_, ringIdx, KR_, joints, 448, 256, nullptr);

    k_sgemm<<<dim3(MJ, 1), 256, 128 * sizeof(float), stream>>>(joints + 256, 448, P6, Y, 128, 128, 128, bb6, 0);
    k_gathermax<<<MJ, 64, KR_ * sizeof(int), stream>>>(Y, 64, J_, ringIdx, KR_, joints, 448, 384, nullptr);

    // ======== joint MLP ========
    k_sgemm<<<dim3(MJ, 2), 256, 448 * sizeof(float), stream>>>(joints, 448, P7, h1, 512, 512, 448, m1b, 1);
    k_sgemm<<<dim3(MJ, 1), 256, 512 * sizeof(float), stream>>>(h1, 512, P8, h2, 256, 256, 512, m2b, 1);
    k_sgemm<<<dim3(MJ, 1), 256, 256 * sizeof(float), stream>>>(h2, 256, P9, (float*)d_out, 3, 3, 256, m3b, 0);
}

// Round 13
// 1159.636 us; speedup vs baseline: 1.1380x; 1.1380x over previous
//
#include <hip/hip_runtime.h>
#include <hip/hip_bf16.h>
#include <float.h>

// Problem constants (from reference setup_inputs)
#define B_   4
#define N_   4096
#define J_   24
#define KR_  4
#define KNN_ 20
#define SLOPE 0.2f
#define SLABN 64             // points per pooling slab
#define NSLAB (N_ / SLABN)   // 64
#define SCAPW 320            // per-wave survivor cap for k_selC3
#define FS_CAP 160           // per-row survivor cap in fused dist+sel
#define KSLACK 8u            // u16-key slack covering split-bf16 error

typedef __attribute__((ext_vector_type(8))) short bf16x8;
typedef __attribute__((ext_vector_type(4))) float f32x4;

// ---------- per-point squared norm ----------
__global__ void k_norm(const float* __restrict__ h, float* __restrict__ xx, int C) {
    int i = blockIdx.x * blockDim.x + threadIdx.x;
    if (i >= B_ * N_) return;
    const float* hp = h + (size_t)i * C;
    float s = 0.f;
    for (int c = 0; c < C; ++c) { float v = hp[c]; s += v * v; }
    xx[i] = s;
}

// ---------- monotone key maps ----------
__device__ __forceinline__ unsigned mapf(float f) {
    unsigned u = __float_as_uint(f);
    return (u & 0x80000000u) ? ~u : (u | 0x80000000u);
}
// top-16 bits of mapf: monotone f32 -> u16 (truncation preserves order)
__device__ __forceinline__ unsigned key16(float f) {
    return mapf(f) >> 16;
}

// ---------- split f32 -> bf16 hi + bf16 lo (both truncated) ----------
__global__ void k_split(const float* __restrict__ h, unsigned short* __restrict__ hi,
                        unsigned short* __restrict__ lo, int total4) {
    int i = blockIdx.x * 256 + threadIdx.x;
    if (i >= total4) return;
    float4 v = ((const float4*)h)[i];
    ushort4 h4, l4;
    {
        unsigned u = __float_as_uint(v.x); h4.x = (unsigned short)(u >> 16);
        float r = v.x - __uint_as_float(u & 0xffff0000u); l4.x = (unsigned short)(__float_as_uint(r) >> 16);
    }
    {
        unsigned u = __float_as_uint(v.y); h4.y = (unsigned short)(u >> 16);
        float r = v.y - __uint_as_float(u & 0xffff0000u); l4.y = (unsigned short)(__float_as_uint(r) >> 16);
    }
    {
        unsigned u = __float_as_uint(v.z); h4.z = (unsigned short)(u >> 16);
        float r = v.z - __uint_as_float(u & 0xffff0000u); l4.z = (unsigned short)(__float_as_uint(r) >> 16);
    }
    {
        unsigned u = __float_as_uint(v.w); h4.w = (unsigned short)(u >> 16);
        float r = v.w - __uint_as_float(u & 0xffff0000u); l4.w = (unsigned short)(__float_as_uint(r) >> 16);
    }
    ((ushort4*)hi)[i] = h4;
    ((ushort4*)lo)[i] = l4;
}

// ---------- ballot-based wave radix select ----------
// r-th smallest (1-indexed) of the 64 lanes' values, low nbits significant.
__device__ __forceinline__ unsigned radixsel_wave(unsigned val, int r, int nbits) {
    unsigned long long cand = ~0ull;
    unsigned prefix = 0;
    for (int bit = nbits - 1; bit >= 0; --bit) {
        unsigned long long z = cand & __ballot(!((val >> bit) & 1u));
        int cz = __popcll(z);
        if (cz >= r) cand = z;
        else { r -= cz; cand &= ~z; prefix |= 1u << bit; }
    }
    return prefix;
}

// exact r-th smallest of S 28-bit packed values (key<<12|col) in LDS
// (lane handles idx lane, lane+64, lane+128). Packed order = (key, col)
// lexicographic; the key-prefix of the r-th packed value equals the exact
// r-th smallest key (col only breaks ties within equal keys).
__device__ __forceinline__ unsigned radixsel_multi28(const unsigned* vals,
                                                     int S, int lane, int r) {
    unsigned k0 = 0, k1 = 0, k2 = 0;
    unsigned act = 0;
    if (lane < S)        { k0 = vals[lane];        act |= 1u; }
    if (lane + 64 < S)   { k1 = vals[lane + 64];   act |= 2u; }
    if (lane + 128 < S)  { k2 = vals[lane + 128];  act |= 4u; }
    unsigned prefix = 0;
    for (int bit = 27; bit >= 0; --bit) {
        unsigned zm = 0; int c = 0;
        if ((act & 1u) && !((k0 >> bit) & 1u)) { zm |= 1u; ++c; }
        if ((act & 2u) && !((k1 >> bit) & 1u)) { zm |= 2u; ++c; }
        if ((act & 4u) && !((k2 >> bit) & 1u)) { zm |= 4u; ++c; }
        unsigned long long b0 = __ballot(c >= 1);
        unsigned long long b1 = __ballot(c >= 2);
        unsigned long long b2 = __ballot(c >= 3);
        int tot = __popcll(b0) + __popcll(b1) + __popcll(b2);
        if (tot >= r) act = zm;
        else { r -= tot; act &= ~zm; prefix |= 1u << bit; }
    }
    return prefix;
}

// Given per-lane u64 key (hi = mapf(d), lo = idx) and active flag: is this lane
// among the 20 smallest active keys? Exact, tie-stable. Pure ballot/popcount.
__device__ __forceinline__ bool top20_round(unsigned long long key, bool active) {
    unsigned hi = (unsigned)(key >> 32);
    unsigned lo = (unsigned)key;
    unsigned long long amask = __ballot(active);
    int navail = __popcll(amask);
    if (navail <= KNN_) return active;
    int r = KNN_;
    unsigned long long cand = amask;
    unsigned prefix = 0;
    for (int bit = 31; bit >= 0; --bit) {
        unsigned long long z = cand & __ballot(!((hi >> bit) & 1u));
        int cz = __popcll(z);
        if (cz >= r) cand = z;
        else { r -= cz; cand &= ~z; prefix |= 1u << bit; }
    }
    unsigned long long c2 = __ballot(active && hi == prefix);
    unsigned p2 = 0;
    for (int bit = 11; bit >= 0; --bit) {
        unsigned long long z = c2 & __ballot(!((lo >> bit) & 1u));
        int cz = __popcll(z);
        if (cz >= r) c2 = z;
        else { r -= cz; c2 &= ~z; p2 |= 1u << bit; }
    }
    return active && (hi < prefix || (hi == prefix && lo <= p2));
}

// Per-wave exact top-20 of skey[0..S); winners ordered via all-pairs rank.
__device__ __forceinline__ void final_top20(const unsigned long long* skey, int S,
                                            unsigned long long* wbuf,
                                            int lane, int* idxout, int obase) {
    unsigned long long key = (lane < S) ? skey[lane] : ~0ull;
    bool active = (lane < S);
    int consumed = (S < 64) ? S : 64;
    int nw = 0;
    for (;;) {
        bool win = top20_round(key, active);
        unsigned long long wb = __ballot(win);
        nw = __popcll(wb);
        int pos = __popcll(wb & ((1ull << lane) - 1ull));
        if (win) wbuf[pos] = key;
        if (consumed >= S) break;
        int src = consumed + lane - nw;
        key = (lane < nw) ? wbuf[lane] : ((src < S) ? skey[src] : ~0ull);
        active = (lane < nw) || (src >= consumed && src < S);
        consumed += 64 - nw;
    }
    if (lane < nw) {
        unsigned long long mine = wbuf[lane];
        int rank = 0;
        for (int i = 0; i < nw; ++i) rank += (wbuf[i] < mine);
        idxout[obase + rank] = (int)(unsigned)mine;
    }
}

// ---------- FUSED distance + top-20 selection (occupancy-first) ----------
// 16-row blocks, 1024-block grid (4 blocks/CU -> 16 waves/CU = 4/SIMD; the
// round-12 version ran 1 wave/SIMD and was pure exposed latency at 447 us).
// XCD-affine batch-major swizzle keeps each batch's X L2-resident (2 XCDs per
// batch). Survivors packed as (key16<<12 | col) in ONE u32 LDS buffer to fit
// the ~24 KB budget. Selection proofs unchanged from rounds 9-11: tau starts
// as (20th-of-lane-mins of first 256 cols)+KSLACK, tightened at it 2/7 by the
// exact 20th packed value (its key prefix = exact 20th key); survivor superset
// holds since KSLACK covers split-bf16 key error; final exact f32 recompute ->
// exact tie-stable top-20. Key matrix never touches global memory.
__global__ __launch_bounds__(256) void k_distsel(const unsigned short* __restrict__ Hi,
                                                 const unsigned short* __restrict__ Lo,
                                                 int C,
                                                 const float* __restrict__ Xall,
                                                 const float* __restrict__ xxall,
                                                 int* __restrict__ knnIdx) {
    __shared__ unsigned short tile[16][256];        // 8 KB, group-swizzled
    __shared__ unsigned pk[16][FS_CAP];             // 10 KB: key16<<12 | col
    __shared__ unsigned long long skey2[4][FS_CAP]; // 5 KB final scratch
    __shared__ unsigned long long wbuf[4][24];
    __shared__ unsigned tauA[16];
    __shared__ int scntA[16];

    int nwg = gridDim.x;                  // 1024 (div by 8 -> bijective swz)
    int cpx = nwg >> 3;
    int bid = blockIdx.x;
    int swz = (bid & 7) * cpx + (bid >> 3);
    int b  = swz >> 8;                    // 256 blocks per batch (batch-major)
    int R0 = (swz & 255) << 4;            // 16-row group

    const unsigned short* XH = Hi + (size_t)b * N_ * C;
    const unsigned short* XL = Lo + (size_t)b * N_ * C;
    const float* Xb  = Xall + (size_t)b * N_ * C;
    const float* xxb = xxall + (size_t)b * N_;
    int* idxout = knnIdx + (size_t)b * N_ * KNN_;
    int tid = threadIdx.x, wv = tid >> 6, lane = tid & 63;
    int lp = lane & 15, kgrp = lane >> 4, rsub = (lane >> 4) * 4;
    int cwoff = wv * 64;
    unsigned long long lmaskLT = (1ull << lane) - 1ull;

    float xxrv = xxb[R0 + lp];

    for (int it = 0; it < 16; ++it) {
        int cb0 = it * 256 + cwoff;
        // ---- MFMA: 16 rows x 64 cols for this wave ----
        f32x4 acc[4];
#pragma unroll
        for (int j = 0; j < 4; ++j) acc[j] = (f32x4){0.f, 0.f, 0.f, 0.f};
        for (int ks = 0; ks < C; ks += 32) {
            int kb = ks + kgrp * 8;
            size_t ro = (size_t)(R0 + lp) * C + kb;
            bf16x8 ah = *(const bf16x8*)(XH + ro);
            bf16x8 al = *(const bf16x8*)(XL + ro);
#pragma unroll
            for (int fj = 0; fj < 4; ++fj) {
                size_t co = (size_t)(cb0 + fj * 16 + lp) * C + kb;
                bf16x8 bh = *(const bf16x8*)(XH + co);
                bf16x8 bl = *(const bf16x8*)(XL + co);
                acc[fj] = __builtin_amdgcn_mfma_f32_16x16x32_bf16(ah, bh, acc[fj], 0, 0, 0);
                acc[fj] = __builtin_amdgcn_mfma_f32_16x16x32_bf16(ah, bl, acc[fj], 0, 0, 0);
                acc[fj] = __builtin_amdgcn_mfma_f32_16x16x32_bf16(al, bh, acc[fj], 0, 0, 0);
            }
        }
        // ---- epilogue: keys into swizzled LDS tile ----
        float xxcv = xxb[cb0 + lane];
#pragma unroll
        for (int fj = 0; fj < 4; ++fj) {
            float xc = __shfl(xxcv, fj * 16 + lp, 64);
#pragma unroll
            for (int r = 0; r < 4; ++r) {
                int row = rsub + r;
                float xr = __shfl(xxrv, row, 64);
                float d = xr + xc - 2.f * acc[fj][r];
                int col = cwoff + fj * 16 + lp;
                int pg = (col >> 3) ^ (row >> 2);
                tile[row][(pg << 3) | (col & 7)] = (unsigned short)key16(d);
            }
        }
        __syncthreads();
        // ---- selection: this wave streams its 4 rows ----
        for (int rr = 0; rr < 4; ++rr) {
            int row = (wv << 2) + rr;
            int pg = (lane >> 1) ^ (row >> 2);
            const unsigned* kp = (const unsigned*)&tile[row][(pg << 3) | ((lane & 1) << 2)];
            unsigned w0 = kp[0], w1 = kp[1];
            unsigned k4[4];
            k4[0] = w0 & 0xffffu; k4[1] = w0 >> 16;
            k4[2] = w1 & 0xffffu; k4[3] = w1 >> 16;
            unsigned mn4 = k4[0];
            mn4 = (k4[1] < mn4) ? k4[1] : mn4;
            mn4 = (k4[2] < mn4) ? k4[2] : mn4;
            mn4 = (k4[3] < mn4) ? k4[3] : mn4;

            unsigned tau;
            int scnt = 0;
            bool doApp;
            if (it == 0) {
                tau = radixsel_wave(mn4, KNN_, 16) + KSLACK;
                if (tau > 0xffffu) tau = 0xffffu;
                doApp = true;
            } else {
                tau = tauA[row];
                doApp = (__ballot(mn4 <= tau) != 0ull);
                if (doApp) scnt = scntA[row];
            }
            if (doApp) {
                int gc = it * 256 + (lane << 2);
#pragma unroll
                for (int t = 0; t < 4; ++t) {
                    bool in = (k4[t] <= tau);
                    unsigned long long m = __ballot(in);
                    int pos = scnt + __popcll(m & lmaskLT);
                    if (in && pos < FS_CAP)
                        pk[row][pos] = (k4[t] << 12) | (unsigned)(gc + t);
                    scnt += __popcll(m);
                }
                if (scnt > FS_CAP) scnt = FS_CAP;
                if (lane == 0) {
                    scntA[row] = scnt;
                    if (it == 0) tauA[row] = tau;
                }
            }
            if (it == 2 || it == 7) {
                // tighten: exact 20th packed -> key threshold (+KSLACK), compact
                int S = scntA[row];
                unsigned p20 = radixsel_multi28(&pk[row][0], S, lane, KNN_);
                unsigned t2 = (p20 >> 12) + KSLACK;
                if (t2 > 0xffffu) t2 = 0xffffu;
                int S2 = 0;
                for (int base = 0; base < S; base += 64) {
                    int si = base + lane;
                    unsigned v = 0; bool in = false;
                    if (si < S) {
                        v = pk[row][si];
                        in = ((v >> 12) <= t2);
                    }
                    unsigned long long m = __ballot(in);
                    int pos = S2 + __popcll(m & lmaskLT);
                    if (in) pk[row][pos] = v;
                    S2 += __popcll(m);
                }
                if (lane == 0) { scntA[row] = S2; tauA[row] = t2; }
            }
        }
        __syncthreads();
    }

    // ---- final: exact recompute + exact tie-stable top-20 per row ----
    for (int rr = 0; rr < 4; ++rr) {
        int row = (wv << 2) + rr;
        int grow = R0 + row;
        int S = scntA[row]; if (S > FS_CAP) S = FS_CAP;
        float xxq = xxb[grow];
        const float4* xq4 = (const float4*)(Xb + (size_t)grow * C);
        unsigned myk[3] = {0xffffffffu, 0xffffffffu, 0xffffffffu};
        unsigned myc[3] = {0u, 0u, 0u};
        unsigned mn = 0xffffffffu;
#pragma unroll
        for (int ch = 0; ch < 3; ++ch) {
            int s = lane + (ch << 6);
            if (s < S) {
                int j = (int)(pk[row][s] & 0xfffu);
                const float4* xj = (const float4*)(Xb + (size_t)j * C);
                float a0 = 0.f, a1 = 0.f, a2 = 0.f, a3 = 0.f;
                for (int c4 = 0; c4 < (C >> 2); ++c4) {
                    float4 x = xj[c4]; float4 qv = xq4[c4];
                    a0 = fmaf(qv.x, x.x, a0);
                    a1 = fmaf(qv.y, x.y, a1);
                    a2 = fmaf(qv.z, x.z, a2);
                    a3 = fmaf(qv.w, x.w, a3);
                }
                float d = xxq + xxb[j] - 2.f * ((a0 + a1) + (a2 + a3));
                unsigned k = mapf(d);
                myk[ch] = k; myc[ch] = (unsigned)j;
                mn = (k < mn) ? k : mn;
            }
        }
        unsigned tau3 = radixsel_wave(mn, KNN_, 32);
        int nch = (S + 63) >> 6;
        int S2 = 0;
#pragma unroll
        for (int ch = 0; ch < 3; ++ch) {
            if (ch >= nch) break;                      // uniform
            bool in = (lane + (ch << 6) < S) && (myk[ch] <= tau3);
            unsigned long long m = __ballot(in);
            int pos = S2 + __popcll(m & lmaskLT);
            if (in) skey2[wv][pos] = ((unsigned long long)myk[ch] << 32) | myc[ch];
            S2 += __popcll(m);
        }
        final_top20(skey2[wv], S2, wbuf[wv], lane, idxout, grow * KNN_);
    }
}

// ---------- layer-1 wave-autonomous dist+select (C=3), exact f32 keys ----------
__global__ __launch_bounds__(256) void k_selC3(const float* __restrict__ V,
                                               const float* __restrict__ xx,
                                               int* __restrict__ knnIdx) {
    __shared__ unsigned long long skey[4][SCAPW];
    __shared__ unsigned long long wbuf[4][24];
    __shared__ int scnt[4];
    int b    = blockIdx.y;
    const float* Xb  = V + (size_t)b * N_ * 3;
    const float* xxb = xx + (size_t)b * N_;
    int* idxout = knnIdx + (size_t)b * N_ * KNN_;
    int wv   = threadIdx.x >> 6;
    int lane = threadIdx.x & 63;
    int q    = blockIdx.x * 4 + wv;
    if (lane == 0) scnt[wv] = 0;

    float qx = Xb[q * 3], qy = Xb[q * 3 + 1], qz = Xb[q * 3 + 2];
    float xxq = xxb[q];

    unsigned kk[64];
#pragma unroll
    for (int cq = 0; cq < 4; ++cq) {
        int jb = (cq * 64 + lane) * 16;
        float pts[48];
        const float4* src = (const float4*)(Xb + (size_t)jb * 3);
#pragma unroll
        for (int t = 0; t < 12; ++t) ((float4*)pts)[t] = src[t];
#pragma unroll
        for (int t = 0; t < 16; ++t) {
            float dot = qx * pts[3 * t];
            dot = fmaf(qy, pts[3 * t + 1], dot);
            dot = fmaf(qz, pts[3 * t + 2], dot);
            float d = xxq + xxb[jb + t] - 2.f * dot;
            kk[cq * 16 + t] = mapf(d);
        }
    }

    unsigned mn = kk[0];
#pragma unroll
    for (int t = 1; t < 64; ++t) mn = (kk[t] < mn) ? kk[t] : mn;
    unsigned tau = radixsel_wave(mn, KNN_, 32);   // exact keys: no slack needed

    int nl = 0;
#pragma unroll
    for (int t = 0; t < 64; ++t) nl += (kk[t] <= tau);
    int p = atomicAdd(&scnt[wv], nl);
#pragma unroll
    for (int cq = 0; cq < 4; ++cq) {
        int jb = (cq * 64 + lane) * 16;
#pragma unroll
        for (int t = 0; t < 16; ++t) {
            if (kk[cq * 16 + t] <= tau) {
                if (p < SCAPW)
                    skey[wv][p] = ((unsigned long long)kk[cq * 16 + t] << 32) | (unsigned)(jb + t);
                ++p;
            }
        }
    }
    int S = scnt[wv];
    if (S > SCAPW) S = SCAPW;
    final_top20(skey[wv], S, wbuf[wv], lane, idxout, q * KNN_);
}

// ---------- fused weight prep ----------
__device__ __forceinline__ void prepP_elem(const float* __restrict__ w,
                                           const float* __restrict__ bias,
                                           int C, int O, float* __restrict__ P,
                                           float* __restrict__ b2, int i) {
    int O2 = 2 * O;
    if (i < O2) b2[i] = (i < O) ? 0.f : bias[i - O];
    if (i >= C * O2) return;
    int k = i / O2, col = i % O2;
    float v;
    if (col < O) v = w[(size_t)col * 2 * C + k];
    else { int o = col - O; v = w[(size_t)o * 2 * C + C + k] - w[(size_t)o * 2 * C + k]; }
    P[i] = v;
}
__device__ __forceinline__ void transp_elem(const float* __restrict__ w, int O, int K,
                                            float* __restrict__ wT, int i) {
    if (i >= O * K) return;
    int k = i / O, o = i % O;
    wT[i] = w[(size_t)o * K + k];
}

__global__ void k_prepall(const float* g1w, const float* g1b,
                          const float* g2w, const float* g2b,
                          const float* g3w, const float* g3b,
                          const float* s1w, const float* s1b,
                          const float* s2w, const float* s2b,
                          const float* s3w, const float* s3b,
                          const float* m1w, const float* m2w, const float* m3w,
                          float* P1, float* P2, float* P3, float* P4, float* P5,
                          float* P6, float* P7, float* P8, float* P9,
                          float* bb1, float* bb2, float* bb3,
                          float* bb4, float* bb5, float* bb6) {
    int i = blockIdx.x * 256 + threadIdx.x;
    switch (blockIdx.y) {
        case 0: prepP_elem(g1w, g1b, 3,   64,  P1, bb1, i); break;
        case 1: prepP_elem(g2w, g2b, 64,  128, P2, bb2, i); break;
        case 2: prepP_elem(g3w, g3b, 128, 256, P3, bb3, i); break;
        case 3: prepP_elem(s1w, s1b, 451, 256, P4, bb4, i); break;
        case 4: prepP_elem(s2w, s2b, 256, 128, P5, bb5, i); break;
        case 5: prepP_elem(s3w, s3b, 128, 64,  P6, bb6, i); break;
        case 6: transp_elem(m1w, 512, 448, P7, i); break;
        case 7: transp_elem(m2w, 256, 512, P8, i); break;
        case 8: transp_elem(m3w, 3,   256, P9, i); break;
    }
}

// ---------- tiled f32 GEMM (large M) ----------
__global__ __launch_bounds__(256) void k_gemm(const float* __restrict__ A, int lda,
                                              const float* __restrict__ Bm,
                                              float* __restrict__ Cm, int ldc,
                                              int M, int N, int K,
                                              const float* __restrict__ bias, int leaky) {
    __shared__ float As[16][68];
    __shared__ float Bs[16][68];
    int tid = threadIdx.x;
    int row0 = blockIdx.y * 64, col0 = blockIdx.x * 64;
    int tr = tid >> 4, tc = tid & 15;
    float acc[4][4] = {{0.f}};
    for (int kt = 0; kt < K; kt += 16) {
#pragma unroll
        for (int i = 0; i < 4; ++i) {
            int e = tid + 256 * i;
            int r = e >> 4, kk = e & 15;
            int gr = row0 + r, gk = kt + kk;
            float v = 0.f;
            if (gr < M && gk < K) v = A[(size_t)gr * lda + gk];
            As[kk][r] = v;
        }
#pragma unroll
        for (int i = 0; i < 4; ++i) {
            int e = tid + 256 * i;
            int kk = e >> 6, c = e & 63;
            int gk = kt + kk, gc = col0 + c;
            float v = 0.f;
            if (gk < K && gc < N) v = Bm[(size_t)gk * N + gc];
            Bs[kk][c] = v;
        }
        __syncthreads();
#pragma unroll
        for (int kk = 0; kk < 16; ++kk) {
            float a[4], bv[4];
            *(float4*)&a[0]  = *(const float4*)&As[kk][tr * 4];
            *(float4*)&bv[0] = *(const float4*)&Bs[kk][tc * 4];
#pragma unroll
            for (int i = 0; i < 4; ++i)
#pragma unroll
                for (int j = 0; j < 4; ++j) acc[i][j] += a[i] * bv[j];
        }
        __syncthreads();
    }
#pragma unroll
    for (int i = 0; i < 4; ++i) {
        int r = row0 + tr * 4 + i;
        if (r >= M) continue;
#pragma unroll
        for (int j = 0; j < 4; ++j) {
            int c = col0 + tc * 4 + j;
            if (c >= N) continue;
            float v = acc[i][j];
            if (bias) v += bias[c];
            if (leaky) v = v >= 0.f ? v : SLOPE * v;
            Cm[(size_t)r * ldc + c] = v;
        }
    }
}

// ---------- small-M GEMM ----------
__global__ __launch_bounds__(256) void k_sgemm(const float* __restrict__ A, int lda,
                                               const float* __restrict__ Bm,
                                               float* __restrict__ Cm, int ldc,
                                               int N, int K,
                                               const float* __restrict__ bias, int leaky) {
    extern __shared__ float Arow[];
    int r   = blockIdx.x;
    int c0  = blockIdx.y * 256;
    int tid = threadIdx.x;
    for (int k = tid; k < K; k += 256) Arow[k] = A[(size_t)r * lda + k];
    __syncthreads();
    int c = c0 + tid;
    if (c >= N) return;
    float acc = bias ? bias[c] : 0.f;
    for (int k = 0; k < K; ++k) acc += Arow[k] * Bm[(size_t)k * N + c];
    if (leaky) acc = acc >= 0.f ? acc : SLOPE * acc;
    Cm[(size_t)r * ldc + c] = acc;
}

// ---------- gather-max epilogue (+ optional fused row-norm) ----------
__global__ void k_gathermax(const float* __restrict__ Y, int O, int R,
                            const int* __restrict__ idx, int kc,
                            float* __restrict__ out, int ldo, int ooff,
                            float* __restrict__ xxout) {
    extern __shared__ int sidx[];
    __shared__ float red[256];
    int br = blockIdx.x;
    int b  = br / R;
    int o  = threadIdx.x;
    if (o < kc) sidx[o] = idx[(size_t)br * kc + o];
    __syncthreads();
    int O2 = 2 * O;
    float z = Y[(size_t)br * O2 + O + o];
    float best = -FLT_MAX;
    for (int k = 0; k < kc; ++k) {
        int m = sidx[k];
        best = fmaxf(best, Y[(size_t)(b * R + m) * O2 + o]);
    }
    float r = z + best;
    r = r >= 0.f ? r : SLOPE * r;
    out[(size_t)br * ldo + ooff + o] = r;
    if (xxout) {
        red[o] = r * r;
        __syncthreads();
        for (int s = blockDim.x >> 1; s > 0; s >>= 1) {
            if (o < s) red[o] += red[o + s];
            __syncthreads();
        }
        if (o == 0) xxout[br] = red[0];
    }
}

// ---------- channel map ----------
__device__ __forceinline__ void chan_map(int b, int c,
                                         const float* Vf, const float* l1,
                                         const float* l2, const float* l3,
                                         const float*& p, int& st) {
    if (c < 3)        { st = 3;   p = Vf + (size_t)b * N_ * 3   + c; }
    else if (c < 67)  { st = 64;  p = l1 + (size_t)b * N_ * 64  + (c - 3); }
    else if (c < 195) { st = 128; p = l2 + (size_t)b * N_ * 128 + (c - 67); }
    else              { st = 256; p = l3 + (size_t)b * N_ * 256 + (c - 195); }
}

// ---------- pooling phase 1 ----------
__global__ __launch_bounds__(256) void k_pool2(const float* __restrict__ Vf,
                                               const float* __restrict__ l1,
                                               const float* __restrict__ l2,
                                               const float* __restrict__ l3,
                                               const float* __restrict__ W,
                                               float* __restrict__ ppool,
                                               float* __restrict__ psw) {
    __shared__ float Wl[SLABN][J_];
    int blk  = blockIdx.x;
    int b    = blk / NSLAB, slab = blk % NSLAB;
    int n0   = slab * SLABN;
    int tid  = threadIdx.x;

    for (int e = tid; e < J_ * SLABN; e += 256) {
        int j = e / SLABN, n = e % SLABN;
        Wl[n][j] = W[((size_t)b * J_ + j) * N_ + n0 + n];
    }
    __syncthreads();

    if (tid < J_) {
        float s = 0.f;
        for (int n = 0; n < SLABN; ++n) s += Wl[n][tid];
        psw[(size_t)blk * J_ + tid] = s;
    }

    int c0 = tid, c1 = tid + 256;
    const float *p0, *p1 = nullptr; int s0, s1 = 0;
    chan_map(b, c0, Vf, l1, l2, l3, p0, s0);
    bool has1 = (c1 < 451);
    if (has1) chan_map(b, c1, Vf, l1, l2, l3, p1, s1);

    float acc0[J_], acc1[J_];
#pragma unroll
    for (int j = 0; j < J_; ++j) { acc0[j] = 0.f; acc1[j] = 0.f; }

    for (int n = 0; n < SLABN; ++n) {
        float v0 = p0[(size_t)(n0 + n) * s0];
        float v1 = has1 ? p1[(size_t)(n0 + n) * s1] : 0.f;
        const float* wn = &Wl[n][0];
#pragma unroll
        for (int q = 0; q < J_ / 4; ++q) {
            float4 w4 = *(const float4*)(wn + 4 * q);
            acc0[4*q+0] += w4.x * v0;  acc1[4*q+0] += w4.x * v1;
            acc0[4*q+1] += w4.y * v0;  acc1[4*q+1] += w4.y * v1;
            acc0[4*q+2] += w4.z * v0;  acc1[4*q+2] += w4.z * v1;
            acc0[4*q+3] += w4.w * v0;  acc1[4*q+3] += w4.w * v1;
        }
    }
    float* pp = ppool + (size_t)blk * J_ * 451;
#pragma unroll
    for (int j = 0; j < J_; ++j) {
        pp[(size_t)j * 451 + c0] = acc0[j];
        if (has1) pp[(size_t)j * 451 + c1] = acc1[j];
    }
}

// ---------- pooling phase 2 ----------
__global__ __launch_bounds__(256) void k_poolred(const float* __restrict__ ppool,
                                                 const float* __restrict__ psw,
                                                 float* __restrict__ pooled) {
    int bj = blockIdx.x;
    int b  = bj / J_, j = bj % J_;
    int tid = threadIdx.x;

    float sw = 0.f;
    for (int sl = 0; sl < NSLAB; ++sl) sw += psw[(size_t)(b * NSLAB + sl) * J_ + j];
    float inv = 1.f / (sw + 1e-5f);

    for (int c = tid; c < 451; c += 256) {
        float s = 0.f;
        for (int sl = 0; sl < NSLAB; ++sl)
            s += ppool[((size_t)(b * NSLAB + sl) * J_ + j) * 451 + c];
        pooled[(size_t)bj * 451 + c] = s * inv;
    }
}

extern "C" void kernel_launch(void* const* d_in, const int* in_sizes, int n_in,
                              void* d_out, int out_size, void* d_ws, size_t ws_size,
                              hipStream_t stream) {
    const float* V  = (const float*)d_in[0];
    const float* W  = (const float*)d_in[1];
    const int* ringIdx = (const int*)d_in[2];
    const float* g1w = (const float*)d_in[3];
    const float* g1b = (const float*)d_in[4];
    const float* g2w = (const float*)d_in[5];
    const float* g2b = (const float*)d_in[6];
    const float* g3w = (const float*)d_in[7];
    const float* g3b = (const float*)d_in[8];
    const float* s1w = (const float*)d_in[9];
    const float* s1b = (const float*)d_in[10];
    const float* s2w = (const float*)d_in[11];
    const float* s2b = (const float*)d_in[12];
    const float* s3w = (const float*)d_in[13];
    const float* s3b = (const float*)d_in[14];
    const float* m1w = (const float*)d_in[15];
    const float* m1b = (const float*)d_in[16];
    const float* m2w = (const float*)d_in[17];
    const float* m2b = (const float*)d_in[18];
    const float* m3w = (const float*)d_in[19];
    const float* m3b = (const float*)d_in[20];
    (void)n_in; (void)in_sizes; (void)out_size; (void)ws_size;

    const int szP1 = 3 * 128,    szP2 = 64 * 256,  szP3 = 128 * 512;
    const int szP4 = 451 * 512,  szP5 = 256 * 256, szP6 = 128 * 128;
    const int szP7 = 448 * 512,  szP8 = 512 * 256, szP9 = 256 * 3;

    // Y/pool region (floats): Y (M*512) and the pooling scratch alias it.
    size_t ymax = (size_t)B_ * N_ * 512;
    size_t pool = (size_t)B_ * NSLAB * J_ * 451 + (size_t)B_ * NSLAB * J_;
    size_t dreg = (ymax > pool) ? ymax : pool;

    // ---- workspace layout (floats) ----
    float* ws = (float*)d_ws;
    size_t off = 0;
    float* l1 = ws + off; off += (size_t)B_ * N_ * 64;
    float* l2 = ws + off; off += (size_t)B_ * N_ * 128;
    float* l3 = ws + off; off += (size_t)B_ * N_ * 256;
    float* xx = ws + off; off += (size_t)B_ * N_;
    float* Y  = ws + off; off += dreg;
    float* ppool = Y;
    float* psw   = Y + (size_t)B_ * NSLAB * J_ * 451;
    unsigned short* Xhi = (unsigned short*)(ws + off); off += (size_t)B_ * N_ * 128 / 2;
    unsigned short* Xlo = (unsigned short*)(ws + off); off += (size_t)B_ * N_ * 128 / 2;
    int* knnIdx = (int*)(ws + off); off += (size_t)B_ * N_ * KNN_;
    float* pooled = ws + off; off += (size_t)B_ * J_ * 451;
    float* joints = ws + off; off += (size_t)B_ * J_ * 448;
    float* h1 = ws + off; off += (size_t)B_ * J_ * 512;
    float* h2 = ws + off; off += (size_t)B_ * J_ * 256;
    float* P1 = ws + off; off += szP1;
    float* P2 = ws + off; off += szP2;
    float* P3 = ws + off; off += szP3;
    float* P4 = ws + off; off += szP4;
    float* P5 = ws + off; off += szP5;
    float* P6 = ws + off; off += szP6;
    float* P7 = ws + off; off += szP7;
    float* P8 = ws + off; off += szP8;
    float* P9 = ws + off; off += szP9;
    float* bb1 = ws + off; off += 128;
    float* bb2 = ws + off; off += 256;
    float* bb3 = ws + off; off += 512;
    float* bb4 = ws + off; off += 512;
    float* bb5 = ws + off; off += 256;
    float* bb6 = ws + off; off += 128;

    const int M = B_ * N_;   // 16384
    const int MJ = B_ * J_;  // 96

    // ---- all weight prep in one launch ----
    k_prepall<<<dim3((szP4 + 255) / 256, 9), 256, 0, stream>>>(
        g1w, g1b, g2w, g2b, g3w, g3b, s1w, s1b, s2w, s2b, s3w, s3b,
        m1w, m2w, m3w, P1, P2, P3, P4, P5, P6, P7, P8, P9,
        bb1, bb2, bb3, bb4, bb5, bb6);

    // ======== geoNet layer 1: C=3 -> O=64 (fused dist+select) ========
    k_norm<<<(M + 255) / 256, 256, 0, stream>>>(V, xx, 3);
    k_selC3<<<dim3(N_ / 4, B_), 256, 0, stream>>>(V, xx, knnIdx);
    k_gemm<<<dim3(2, M / 64), 256, 0, stream>>>(V, 3, P1, Y, 128, M, 128, 3, bb1, 0);
    k_gathermax<<<M, 64, KNN_ * sizeof(int), stream>>>(Y, 64, N_, knnIdx, KNN_, l1, 64, 0, xx);

    // ======== layer 2: C=64 -> O=128 (fused dist+select, 16-row blocks) ========
    k_split<<<(M * 64 / 4 + 255) / 256, 256, 0, stream>>>(l1, Xhi, Xlo, M * 64 / 4);
    k_distsel<<<dim3((N_ / 16) * B_), 256, 0, stream>>>(Xhi, Xlo, 64, l1, xx, knnIdx);
    k_gemm<<<dim3(4, M / 64), 256, 0, stream>>>(l1, 64, P2, Y, 256, M, 256, 64, bb2, 0);
    k_gathermax<<<M, 128, KNN_ * sizeof(int), stream>>>(Y, 128, N_, knnIdx, KNN_, l2, 128, 0, xx);

    // ======== layer 3: C=128 -> O=256 (fused dist+select, 16-row blocks) ========
    k_split<<<(M * 128 / 4 + 255) / 256, 256, 0, stream>>>(l2, Xhi, Xlo, M * 128 / 4);
    k_distsel<<<dim3((N_ / 16) * B_), 256, 0, stream>>>(Xhi, Xlo, 128, l2, xx, knnIdx);
    k_gemm<<<dim3(8, M / 64), 256, 0, stream>>>(l2, 128, P3, Y, 512, M, 512, 128, bb3, 0);
    k_gathermax<<<M, 256, KNN_ * sizeof(int), stream>>>(Y, 256, N_, knnIdx, KNN_, l3, 256, 0, nullptr);

    // ======== pooling onto joints ========
    k_pool2<<<B_ * NSLAB, 256, 0, stream>>>(V, l1, l2, l3, W, ppool, psw);
    k_poolred<<<MJ, 256, 0, stream>>>(ppool, psw, pooled);

    // ======== skeleton convs ========
    k_sgemm<<<dim3(MJ, 2), 256, 451 * sizeof(float), stream>>>(pooled, 451, P4, Y, 512, 512, 451, bb4, 0);
    k_gathermax<<<MJ, 256, KR_ * sizeof(int), stream>>>(Y, 256, J_, ringIdx, KR_, joints, 448, 0, nullptr);

    k_sgemm<<<dim3(MJ, 1), 256, 256 * sizeof(float), stream>>>(joints, 448, P5, Y, 256, 256, 256, bb5, 0);
    k_gathermax<<<MJ, 128, KR_ * sizeof(int), stream>>>(Y, 128, J_, ringIdx, KR_, joints, 448, 256, nullptr);

    k_sgemm<<<dim3(MJ, 1), 256, 128 * sizeof(float), stream>>>(joints + 256, 448, P6, Y, 128, 128, 128, bb6, 0);
    k_gathermax<<<MJ, 64, KR_ * sizeof(int), stream>>>(Y, 64, J_, ringIdx, KR_, joints, 448, 384, nullptr);

    // ======== joint MLP ========
    k_sgemm<<<dim3(MJ, 2), 256, 448 * sizeof(float), stream>>>(joints, 448, P7, h1, 512, 512, 448, m1b, 1);
    k_sgemm<<<dim3(MJ, 1), 256, 512 * sizeof(float), stream>>>(h1, 512, P8, h2, 256, 256, 512, m2b, 1);
    k_sgemm<<<dim3(MJ, 1), 256, 256 * sizeof(float), stream>>>(h2, 256, P9, (float*)d_out, 3, 3, 256, m3b, 0);
}

// Round 14
// 849.080 us; speedup vs baseline: 1.5542x; 1.3658x over previous
//
#include <hip/hip_runtime.h>
#include <hip/hip_bf16.h>
#include <float.h>

// Problem constants (from reference setup_inputs)
#define B_   4
#define N_   4096
#define J_   24
#define KR_  4
#define KNN_ 20
#define SLOPE 0.2f
#define SLABN 64             // points per pooling slab
#define NSLAB (N_ / SLABN)   // 64
#define NTILE 32             // 128-wide tiles per dim
#define SCAPW 320            // per-wave survivor cap (exp. S ~ 30-50)
#define KSLACK 8u            // u16-key slack covering split-bf16 error

typedef __attribute__((ext_vector_type(8))) short bf16x8;
typedef __attribute__((ext_vector_type(4))) float f32x4;

// ---------- per-point squared norm ----------
__global__ void k_norm(const float* __restrict__ h, float* __restrict__ xx, int C) {
    int i = blockIdx.x * blockDim.x + threadIdx.x;
    if (i >= B_ * N_) return;
    const float* hp = h + (size_t)i * C;
    float s = 0.f;
    for (int c = 0; c < C; ++c) { float v = hp[c]; s += v * v; }
    xx[i] = s;
}

// ---------- monotone key maps ----------
__device__ __forceinline__ unsigned mapf(float f) {
    unsigned u = __float_as_uint(f);
    return (u & 0x80000000u) ? ~u : (u | 0x80000000u);
}
// top-16 bits of mapf: monotone f32 -> u16 (truncation preserves order)
__device__ __forceinline__ unsigned key16(float f) {
    return mapf(f) >> 16;
}

// ---------- split f32 -> bf16 hi + bf16 lo (both truncated; x = hi + lo + r, |r|<=2^-16|x|) ----------
__global__ void k_split(const float* __restrict__ h, unsigned short* __restrict__ hi,
                        unsigned short* __restrict__ lo, int total4) {
    int i = blockIdx.x * 256 + threadIdx.x;
    if (i >= total4) return;
    float4 v = ((const float4*)h)[i];
    ushort4 h4, l4;
    {
        unsigned u = __float_as_uint(v.x); h4.x = (unsigned short)(u >> 16);
        float r = v.x - __uint_as_float(u & 0xffff0000u); l4.x = (unsigned short)(__float_as_uint(r) >> 16);
    }
    {
        unsigned u = __float_as_uint(v.y); h4.y = (unsigned short)(u >> 16);
        float r = v.y - __uint_as_float(u & 0xffff0000u); l4.y = (unsigned short)(__float_as_uint(r) >> 16);
    }
    {
        unsigned u = __float_as_uint(v.z); h4.z = (unsigned short)(u >> 16);
        float r = v.z - __uint_as_float(u & 0xffff0000u); l4.z = (unsigned short)(__float_as_uint(r) >> 16);
    }
    {
        unsigned u = __float_as_uint(v.w); h4.w = (unsigned short)(u >> 16);
        float r = v.w - __uint_as_float(u & 0xffff0000u); l4.w = (unsigned short)(__float_as_uint(r) >> 16);
    }
    ((ushort4*)hi)[i] = h4;
    ((ushort4*)lo)[i] = l4;
}

// ---------- group swizzle for the key tile ----------
// Physical u16 index within a 128-u16 row: group (col>>3) XORed with swz(row),
// offset (col&7) unchanged. Whole 16B groups move -> uint4 stays aligned.
// Mirror-gather (rows g*8+q at fixed q) sees swz vary with g -> banks spread
// (16-way -> ~4-way); the (row>>2) bit separates the epilogue's 4 row
// subgroups so writes stay ~2-way.
__device__ __forceinline__ int swz_(int row) {
    return ((row >> 3) & 7) ^ (((row >> 2) & 1) << 2);
}

// ---------- MFMA distance GEMM (split-bf16, 3-pass) -> u16 keys ----------
__global__ __launch_bounds__(256) void k_dist(const unsigned short* __restrict__ Hi,
                                              const unsigned short* __restrict__ Lo,
                                              int C,
                                              const float* __restrict__ xxall,
                                              unsigned short* __restrict__ Dall, int b0) {
    __shared__ unsigned short tile[128][128];   // swizzled groups; 32 KiB
    int b = b0 + blockIdx.y;
    const unsigned short* XH = Hi + (size_t)b * N_ * C;
    const unsigned short* XL = Lo + (size_t)b * N_ * C;
    const float* xxb = xxall + (size_t)b * N_;
    unsigned short* D = Dall + (size_t)blockIdx.y * N_ * N_;

    int t = blockIdx.x;                      // linear upper-tri tile id
    int ti = 0;
    while (t >= NTILE - ti) { t -= NTILE - ti; ++ti; }
    int tj = ti + t;
    int row0 = ti * 128, col0 = tj * 128;
    int tid  = threadIdx.x;
    int wv   = tid >> 6, lane = tid & 63;
    int wr   = wv >> 1,  wc   = wv & 1;
    int rbase = row0 + wr * 64;
    int cbase = col0 + wc * 64;
    int lp    = lane & 15;        // point within frag
    int kgrp  = lane >> 4;        // k-group

    f32x4 acc[4][4];
#pragma unroll
    for (int i = 0; i < 4; ++i)
#pragma unroll
        for (int j = 0; j < 4; ++j) acc[i][j] = (f32x4){0.f, 0.f, 0.f, 0.f};

    for (int ks = 0; ks < C; ks += 32) {
        int kb = ks + kgrp * 8;
        bf16x8 ah[4], al[4];
#pragma unroll
        for (int fi = 0; fi < 4; ++fi) {
            size_t ro = (size_t)(rbase + fi * 16 + lp) * C + kb;
            ah[fi] = *(const bf16x8*)(XH + ro);
            al[fi] = *(const bf16x8*)(XL + ro);
        }
#pragma unroll
        for (int fj = 0; fj < 4; ++fj) {
            size_t co = (size_t)(cbase + fj * 16 + lp) * C + kb;
            bf16x8 bh = *(const bf16x8*)(XH + co);
            bf16x8 bl = *(const bf16x8*)(XL + co);
#pragma unroll
            for (int fi = 0; fi < 4; ++fi) {
                acc[fi][fj] = __builtin_amdgcn_mfma_f32_16x16x32_bf16(ah[fi], bh, acc[fi][fj], 0, 0, 0);
                acc[fi][fj] = __builtin_amdgcn_mfma_f32_16x16x32_bf16(ah[fi], bl, acc[fi][fj], 0, 0, 0);
                acc[fi][fj] = __builtin_amdgcn_mfma_f32_16x16x32_bf16(al[fi], bh, acc[fi][fj], 0, 0, 0);
            }
        }
    }

    // epilogue: d = xxr + xxc - 2*dot -> u16 key into swizzled LDS tile.
    // xx broadcast via shuffles (r4-proven register profile: no dependent
    // VMEM in the epilogue).
    float xxrv = xxb[rbase + lane];
    float xxcv = xxb[cbase + lane];
    int rsub = (lane >> 4) * 4;
#pragma unroll
    for (int fi = 0; fi < 4; ++fi) {
#pragma unroll
        for (int fj = 0; fj < 4; ++fj) {
            float xc = __shfl(xxcv, fj * 16 + lp, 64);
#pragma unroll
            for (int r = 0; r < 4; ++r) {
                float xr = __shfl(xxrv, fi * 16 + rsub + r, 64);
                float d = xr + xc - 2.f * acc[fi][fj][r];
                int row = wr * 64 + fi * 16 + rsub + r;
                int col = wc * 64 + fj * 16 + lp;
                tile[row][(((col >> 3) ^ swz_(row)) << 3) | (col & 7)] =
                    (unsigned short)key16(d);
            }
        }
    }
    __syncthreads();

    // normal store: 16-lane groups each write 256 B contiguous (one full row)
    {
        int r0  = tid >> 4;             // 0..15
        int grp = tid & 15;             // logical 8-u16 group
#pragma unroll
        for (int q = 0; q < 8; ++q) {
            int row = r0 + q * 16;
            *(uint4*)(D + (size_t)(row0 + row) * N_ + col0 + grp * 8) =
                *(const uint4*)&tile[row][(grp ^ swz_(row)) << 3];
        }
    }
    if (ti == tj) return;
    // mirror store: transpose gather from swizzled LDS; 16-lane groups write
    // 256 B contiguous
    {
        int c0g = tid >> 4;             // base column group 0..15
        int g   = tid & 15;             // lane within group -> row segment g*8
#pragma unroll
        for (int cq = 0; cq < 8; ++cq) {
            int c  = c0g + cq * 16;
            int cg = c >> 3, co = c & 7;
            unsigned short s[8];
#pragma unroll
            for (int q = 0; q < 8; ++q) {
                int row = g * 8 + q;
                s[q] = tile[row][((cg ^ swz_(row)) << 3) | co];
            }
            *(uint4*)(D + (size_t)(col0 + c) * N_ + row0 + g * 8) = *(const uint4*)s;
        }
    }
}

// ---------- ballot-based wave radix select (no dependent shuffle chains) ----------
// r-th smallest (1-indexed) of the 64 lanes' values, low nbits significant.
__device__ __forceinline__ unsigned radixsel_wave(unsigned val, int r, int nbits) {
    unsigned long long cand = ~0ull;
    unsigned prefix = 0;
    for (int bit = nbits - 1; bit >= 0; --bit) {
        unsigned long long z = cand & __ballot(!((val >> bit) & 1u));
        int cz = __popcll(z);
        if (cz >= r) cand = z;
        else { r -= cz; cand &= ~z; prefix |= 1u << bit; }
    }
    return prefix;
}

// Given per-lane u64 key (hi = mapf(d), lo = idx) and an active flag, return
// whether this lane is among the 20 smallest (u64 order) active keys.
// Exact, tie-stable (idx is unique). Pure ballot/popcount — no shuffle chains.
__device__ __forceinline__ bool top20_round(unsigned long long key, bool active) {
    unsigned hi = (unsigned)(key >> 32);
    unsigned lo = (unsigned)key;
    unsigned long long amask = __ballot(active);
    int navail = __popcll(amask);
    if (navail <= KNN_) return active;
    int r = KNN_;
    unsigned long long cand = amask;
    unsigned prefix = 0;
    for (int bit = 31; bit >= 0; --bit) {
        unsigned long long z = cand & __ballot(!((hi >> bit) & 1u));
        int cz = __popcll(z);
        if (cz >= r) cand = z;
        else { r -= cz; cand &= ~z; prefix |= 1u << bit; }
    }
    unsigned long long c2 = __ballot(active && hi == prefix);
    unsigned p2 = 0;
    for (int bit = 11; bit >= 0; --bit) {          // idx < 4096 -> 12 bits
        unsigned long long z = c2 & __ballot(!((lo >> bit) & 1u));
        int cz = __popcll(z);
        if (cz >= r) c2 = z;
        else { r -= cz; c2 &= ~z; p2 |= 1u << bit; }
    }
    return active && (hi < prefix || (hi == prefix && lo <= p2));
}

// Per-wave exact top-20 of skey[0..S) via rounds of ballot select; winners
// ordered by all-pairs rank over 20 elements in LDS (no chains, no barriers).
__device__ __forceinline__ void final_top20(const unsigned long long* skey, int S,
                                            unsigned long long* wbuf,
                                            int lane, int* idxout, int obase) {
    unsigned long long key = (lane < S) ? skey[lane] : ~0ull;
    bool active = (lane < S);
    int consumed = (S < 64) ? S : 64;
    int nw = 0;
    for (;;) {
        bool win = top20_round(key, active);
        unsigned long long wb = __ballot(win);
        nw = __popcll(wb);
        int pos = __popcll(wb & ((1ull << lane) - 1ull));
        if (win) wbuf[pos] = key;
        if (consumed >= S) break;
        int src = consumed + lane - nw;
        key = (lane < nw) ? wbuf[lane] : ((src < S) ? skey[src] : ~0ull);
        active = (lane < nw) || (src >= consumed && src < S);
        consumed += 64 - nw;
    }
    if (lane < nw) {
        unsigned long long mine = wbuf[lane];
        int rank = 0;
        for (int i = 0; i < nw; ++i) rank += (wbuf[i] < mine);
        idxout[obase + rank] = (int)(unsigned)mine;
    }
}

// ---------- wave-autonomous top-20 from u16 key rows ----------
// One wave = one full row (64 keys/lane). tau = 20th-smallest of the 64
// lane-mins (each lane-min is a data value; the 20 smallest lane-mins are 20
// distinct values <= B, so B >= row's true 20th) + KSLACK for split-bf16 key
// error (2*delta bound, margin ~1e4x) -> survivor superset. Survivors' exact
// f32 distances recomputed; exact tie-stable top-20 via ballot radix select.
// No __syncthreads anywhere — 4 independent rows per block.
__global__ __launch_bounds__(256) void k_sel(const unsigned short* __restrict__ Dall,
                                             const float* __restrict__ Xall, int C,
                                             const float* __restrict__ xxall,
                                             int* __restrict__ knnIdx, int b0) {
    __shared__ unsigned short sidx[4][SCAPW];
    __shared__ unsigned long long skey[4][SCAPW];
    __shared__ unsigned long long wbuf[4][24];
    __shared__ int scnt[4];
    int b = b0 + blockIdx.y;
    const unsigned short* Db = Dall + (size_t)blockIdx.y * N_ * N_;
    const float* Xb  = Xall + (size_t)b * N_ * C;
    const float* xxb = xxall + (size_t)b * N_;
    int* idxout = knnIdx + (size_t)b * N_ * KNN_;
    int wv   = threadIdx.x >> 6;
    int lane = threadIdx.x & 63;
    int ql   = blockIdx.x * 4 + wv;
    if (lane == 0) scnt[wv] = 0;

    const uint4* row = (const uint4*)(Db + (size_t)ql * N_);
    uint4 K[8];
#pragma unroll
    for (int q = 0; q < 8; ++q) K[q] = row[q * 64 + lane];

    // per-lane min of its 64 keys
    unsigned mn = 0xffffu;
#pragma unroll
    for (int q = 0; q < 8; ++q) {
        const unsigned* w = (const unsigned*)&K[q];
#pragma unroll
        for (int h = 0; h < 4; ++h) {
            unsigned lo = w[h] & 0xffffu, hi = w[h] >> 16;
            mn = (lo < mn) ? lo : mn;
            mn = (hi < mn) ? hi : mn;
        }
    }
    unsigned tau = radixsel_wave(mn, KNN_, 16) + KSLACK;
    if (tau > 0xffffu) tau = 0xffffu;

    // count per-lane survivors, reserve a private range with ONE wave-wide atomic
    int nl = 0;
#pragma unroll
    for (int q = 0; q < 8; ++q) {
        const unsigned* w = (const unsigned*)&K[q];
#pragma unroll
        for (int h = 0; h < 4; ++h) {
            nl += ((w[h] & 0xffffu) <= tau);
            nl += ((w[h] >> 16) <= tau);
        }
    }
    int p = atomicAdd(&scnt[wv], nl);
#pragma unroll
    for (int q = 0; q < 8; ++q) {
        const unsigned* w = (const unsigned*)&K[q];
        int jb = (q * 64 + lane) * 8;
#pragma unroll
        for (int h = 0; h < 4; ++h) {
            if ((w[h] & 0xffffu) <= tau) { if (p < SCAPW) sidx[wv][p] = (unsigned short)(jb + 2 * h);     ++p; }
            if ((w[h] >> 16)     <= tau) { if (p < SCAPW) sidx[wv][p] = (unsigned short)(jb + 2 * h + 1); ++p; }
        }
    }
    int S = scnt[wv];                 // wave-ordered LDS: atomic precedes this read
    if (S > SCAPW) S = SCAPW;

    // recompute exact f32 distances for survivors (X rows are L2-resident)
    float xxq = xxb[ql];
    const float4* xq4 = (const float4*)(Xb + (size_t)ql * C);
    for (int s = lane; s < S; s += 64) {
        int j = (int)sidx[wv][s];
        const float4* xj = (const float4*)(Xb + (size_t)j * C);
        float a0 = 0.f, a1 = 0.f, a2 = 0.f, a3 = 0.f;
        for (int c4 = 0; c4 < (C >> 2); ++c4) {
            float4 x = xj[c4]; float4 qv = xq4[c4];
            a0 = fmaf(qv.x, x.x, a0);
            a1 = fmaf(qv.y, x.y, a1);
            a2 = fmaf(qv.z, x.z, a2);
            a3 = fmaf(qv.w, x.w, a3);
        }
        float dot = (a0 + a1) + (a2 + a3);
        float d = xxq + xxb[j] - 2.f * dot;
        skey[wv][s] = ((unsigned long long)mapf(d) << 32) | (unsigned)j;
    }
    final_top20(skey[wv], S, wbuf[wv], lane, idxout, ql * KNN_);
}

// ---------- layer-1 wave-autonomous dist+select (C=3), exact f32 keys ----------
__global__ __launch_bounds__(256) void k_selC3(const float* __restrict__ V,
                                               const float* __restrict__ xx,
                                               int* __restrict__ knnIdx) {
    __shared__ unsigned long long skey[4][SCAPW];
    __shared__ unsigned long long wbuf[4][24];
    __shared__ int scnt[4];
    int b    = blockIdx.y;
    const float* Xb  = V + (size_t)b * N_ * 3;
    const float* xxb = xx + (size_t)b * N_;
    int* idxout = knnIdx + (size_t)b * N_ * KNN_;
    int wv   = threadIdx.x >> 6;
    int lane = threadIdx.x & 63;
    int q    = blockIdx.x * 4 + wv;
    if (lane == 0) scnt[wv] = 0;

    float qx = Xb[q * 3], qy = Xb[q * 3 + 1], qz = Xb[q * 3 + 2];
    float xxq = xxb[q];

    unsigned kk[64];
#pragma unroll
    for (int cq = 0; cq < 4; ++cq) {
        int jb = (cq * 64 + lane) * 16;
        float pts[48];
        const float4* src = (const float4*)(Xb + (size_t)jb * 3);
#pragma unroll
        for (int t = 0; t < 12; ++t) ((float4*)pts)[t] = src[t];
#pragma unroll
        for (int t = 0; t < 16; ++t) {
            float dot = qx * pts[3 * t];
            dot = fmaf(qy, pts[3 * t + 1], dot);
            dot = fmaf(qz, pts[3 * t + 2], dot);
            float d = xxq + xxb[jb + t] - 2.f * dot;
            kk[cq * 16 + t] = mapf(d);
        }
    }

    unsigned mn = kk[0];
#pragma unroll
    for (int t = 1; t < 64; ++t) mn = (kk[t] < mn) ? kk[t] : mn;
    unsigned tau = radixsel_wave(mn, KNN_, 32);   // exact keys: no slack needed

    int nl = 0;
#pragma unroll
    for (int t = 0; t < 64; ++t) nl += (kk[t] <= tau);
    int p = atomicAdd(&scnt[wv], nl);
#pragma unroll
    for (int cq = 0; cq < 4; ++cq) {
        int jb = (cq * 64 + lane) * 16;
#pragma unroll
        for (int t = 0; t < 16; ++t) {
            if (kk[cq * 16 + t] <= tau) {
                if (p < SCAPW)
                    skey[wv][p] = ((unsigned long long)kk[cq * 16 + t] << 32) | (unsigned)(jb + t);
                ++p;
            }
        }
    }
    int S = scnt[wv];
    if (S > SCAPW) S = SCAPW;
    final_top20(skey[wv], S, wbuf[wv], lane, idxout, q * KNN_);
}

// ---------- fused weight prep ----------
__device__ __forceinline__ void prepP_elem(const float* __restrict__ w,
                                           const float* __restrict__ bias,
                                           int C, int O, float* __restrict__ P,
                                           float* __restrict__ b2, int i) {
    int O2 = 2 * O;
    if (i < O2) b2[i] = (i < O) ? 0.f : bias[i - O];
    if (i >= C * O2) return;
    int k = i / O2, col = i % O2;
    float v;
    if (col < O) v = w[(size_t)col * 2 * C + k];
    else { int o = col - O; v = w[(size_t)o * 2 * C + C + k] - w[(size_t)o * 2 * C + k]; }
    P[i] = v;
}
__device__ __forceinline__ void transp_elem(const float* __restrict__ w, int O, int K,
                                            float* __restrict__ wT, int i) {
    if (i >= O * K) return;
    int k = i / O, o = i % O;
    wT[i] = w[(size_t)o * K + k];
}

__global__ void k_prepall(const float* g1w, const float* g1b,
                          const float* g2w, const float* g2b,
                          const float* g3w, const float* g3b,
                          const float* s1w, const float* s1b,
                          const float* s2w, const float* s2b,
                          const float* s3w, const float* s3b,
                          const float* m1w, const float* m2w, const float* m3w,
                          float* P1, float* P2, float* P3, float* P4, float* P5,
                          float* P6, float* P7, float* P8, float* P9,
                          float* bb1, float* bb2, float* bb3,
                          float* bb4, float* bb5, float* bb6) {
    int i = blockIdx.x * 256 + threadIdx.x;
    switch (blockIdx.y) {
        case 0: prepP_elem(g1w, g1b, 3,   64,  P1, bb1, i); break;
        case 1: prepP_elem(g2w, g2b, 64,  128, P2, bb2, i); break;
        case 2: prepP_elem(g3w, g3b, 128, 256, P3, bb3, i); break;
        case 3: prepP_elem(s1w, s1b, 451, 256, P4, bb4, i); break;
        case 4: prepP_elem(s2w, s2b, 256, 128, P5, bb5, i); break;
        case 5: prepP_elem(s3w, s3b, 128, 64,  P6, bb6, i); break;
        case 6: transp_elem(m1w, 512, 448, P7, i); break;
        case 7: transp_elem(m2w, 256, 512, P8, i); break;
        case 8: transp_elem(m3w, 3,   256, P9, i); break;
    }
}

// ---------- tiled f32 GEMM (large M) ----------
__global__ __launch_bounds__(256) void k_gemm(const float* __restrict__ A, int lda,
                                              const float* __restrict__ Bm,
                                              float* __restrict__ Cm, int ldc,
                                              int M, int N, int K,
                                              const float* __restrict__ bias, int leaky) {
    __shared__ float As[16][68];
    __shared__ float Bs[16][68];
    int tid = threadIdx.x;
    int row0 = blockIdx.y * 64, col0 = blockIdx.x * 64;
    int tr = tid >> 4, tc = tid & 15;
    float acc[4][4] = {{0.f}};
    for (int kt = 0; kt < K; kt += 16) {
#pragma unroll
        for (int i = 0; i < 4; ++i) {
            int e = tid + 256 * i;
            int r = e >> 4, kk = e & 15;
            int gr = row0 + r, gk = kt + kk;
            float v = 0.f;
            if (gr < M && gk < K) v = A[(size_t)gr * lda + gk];
            As[kk][r] = v;
        }
#pragma unroll
        for (int i = 0; i < 4; ++i) {
            int e = tid + 256 * i;
            int kk = e >> 6, c = e & 63;
            int gk = kt + kk, gc = col0 + c;
            float v = 0.f;
            if (gk < K && gc < N) v = Bm[(size_t)gk * N + gc];
            Bs[kk][c] = v;
        }
        __syncthreads();
#pragma unroll
        for (int kk = 0; kk < 16; ++kk) {
            float a[4], bv[4];
            *(float4*)&a[0]  = *(const float4*)&As[kk][tr * 4];
            *(float4*)&bv[0] = *(const float4*)&Bs[kk][tc * 4];
#pragma unroll
            for (int i = 0; i < 4; ++i)
#pragma unroll
                for (int j = 0; j < 4; ++j) acc[i][j] += a[i] * bv[j];
        }
        __syncthreads();
    }
#pragma unroll
    for (int i = 0; i < 4; ++i) {
        int r = row0 + tr * 4 + i;
        if (r >= M) continue;
#pragma unroll
        for (int j = 0; j < 4; ++j) {
            int c = col0 + tc * 4 + j;
            if (c >= N) continue;
            float v = acc[i][j];
            if (bias) v += bias[c];
            if (leaky) v = v >= 0.f ? v : SLOPE * v;
            Cm[(size_t)r * ldc + c] = v;
        }
    }
}

// ---------- small-M GEMM ----------
__global__ __launch_bounds__(256) void k_sgemm(const float* __restrict__ A, int lda,
                                               const float* __restrict__ Bm,
                                               float* __restrict__ Cm, int ldc,
                                               int N, int K,
                                               const float* __restrict__ bias, int leaky) {
    extern __shared__ float Arow[];
    int r   = blockIdx.x;
    int c0  = blockIdx.y * 256;
    int tid = threadIdx.x;
    for (int k = tid; k < K; k += 256) Arow[k] = A[(size_t)r * lda + k];
    __syncthreads();
    int c = c0 + tid;
    if (c >= N) return;
    float acc = bias ? bias[c] : 0.f;
    for (int k = 0; k < K; ++k) acc += Arow[k] * Bm[(size_t)k * N + c];
    if (leaky) acc = acc >= 0.f ? acc : SLOPE * acc;
    Cm[(size_t)r * ldc + c] = acc;
}

// ---------- gather-max epilogue (+ optional fused row-norm) ----------
__global__ void k_gathermax(const float* __restrict__ Y, int O, int R,
                            const int* __restrict__ idx, int kc,
                            float* __restrict__ out, int ldo, int ooff,
                            float* __restrict__ xxout) {
    extern __shared__ int sidx[];
    __shared__ float red[256];
    int br = blockIdx.x;
    int b  = br / R;
    int o  = threadIdx.x;
    if (o < kc) sidx[o] = idx[(size_t)br * kc + o];
    __syncthreads();
    int O2 = 2 * O;
    float z = Y[(size_t)br * O2 + O + o];
    float best = -FLT_MAX;
    for (int k = 0; k < kc; ++k) {
        int m = sidx[k];
        best = fmaxf(best, Y[(size_t)(b * R + m) * O2 + o]);
    }
    float r = z + best;
    r = r >= 0.f ? r : SLOPE * r;
    out[(size_t)br * ldo + ooff + o] = r;
    if (xxout) {
        red[o] = r * r;
        __syncthreads();
        for (int s = blockDim.x >> 1; s > 0; s >>= 1) {
            if (o < s) red[o] += red[o + s];
            __syncthreads();
        }
        if (o == 0) xxout[br] = red[0];
    }
}

// ---------- channel map ----------
__device__ __forceinline__ void chan_map(int b, int c,
                                         const float* Vf, const float* l1,
                                         const float* l2, const float* l3,
                                         const float*& p, int& st) {
    if (c < 3)        { st = 3;   p = Vf + (size_t)b * N_ * 3   + c; }
    else if (c < 67)  { st = 64;  p = l1 + (size_t)b * N_ * 64  + (c - 3); }
    else if (c < 195) { st = 128; p = l2 + (size_t)b * N_ * 128 + (c - 67); }
    else              { st = 256; p = l3 + (size_t)b * N_ * 256 + (c - 195); }
}

// ---------- pooling phase 1 ----------
__global__ __launch_bounds__(256) void k_pool2(const float* __restrict__ Vf,
                                               const float* __restrict__ l1,
                                               const float* __restrict__ l2,
                                               const float* __restrict__ l3,
                                               const float* __restrict__ W,
                                               float* __restrict__ ppool,
                                               float* __restrict__ psw) {
    __shared__ float Wl[SLABN][J_];
    int blk  = blockIdx.x;
    int b    = blk / NSLAB, slab = blk % NSLAB;
    int n0   = slab * SLABN;
    int tid  = threadIdx.x;

    for (int e = tid; e < J_ * SLABN; e += 256) {
        int j = e / SLABN, n = e % SLABN;
        Wl[n][j] = W[((size_t)b * J_ + j) * N_ + n0 + n];
    }
    __syncthreads();

    if (tid < J_) {
        float s = 0.f;
        for (int n = 0; n < SLABN; ++n) s += Wl[n][tid];
        psw[(size_t)blk * J_ + tid] = s;
    }

    int c0 = tid, c1 = tid + 256;
    const float *p0, *p1 = nullptr; int s0, s1 = 0;
    chan_map(b, c0, Vf, l1, l2, l3, p0, s0);
    bool has1 = (c1 < 451);
    if (has1) chan_map(b, c1, Vf, l1, l2, l3, p1, s1);

    float acc0[J_], acc1[J_];
#pragma unroll
    for (int j = 0; j < J_; ++j) { acc0[j] = 0.f; acc1[j] = 0.f; }

    for (int n = 0; n < SLABN; ++n) {
        float v0 = p0[(size_t)(n0 + n) * s0];
        float v1 = has1 ? p1[(size_t)(n0 + n) * s1] : 0.f;
        const float* wn = &Wl[n][0];
#pragma unroll
        for (int q = 0; q < J_ / 4; ++q) {
            float4 w4 = *(const float4*)(wn + 4 * q);
            acc0[4*q+0] += w4.x * v0;  acc1[4*q+0] += w4.x * v1;
            acc0[4*q+1] += w4.y * v0;  acc1[4*q+1] += w4.y * v1;
            acc0[4*q+2] += w4.z * v0;  acc1[4*q+2] += w4.z * v1;
            acc0[4*q+3] += w4.w * v0;  acc1[4*q+3] += w4.w * v1;
        }
    }
    float* pp = ppool + (size_t)blk * J_ * 451;
#pragma unroll
    for (int j = 0; j < J_; ++j) {
        pp[(size_t)j * 451 + c0] = acc0[j];
        if (has1) pp[(size_t)j * 451 + c1] = acc1[j];
    }
}

// ---------- pooling phase 2 ----------
__global__ __launch_bounds__(256) void k_poolred(const float* __restrict__ ppool,
                                                 const float* __restrict__ psw,
                                                 float* __restrict__ pooled) {
    int bj = blockIdx.x;
    int b  = bj / J_, j = bj % J_;
    int tid = threadIdx.x;

    float sw = 0.f;
    for (int sl = 0; sl < NSLAB; ++sl) sw += psw[(size_t)(b * NSLAB + sl) * J_ + j];
    float inv = 1.f / (sw + 1e-5f);

    for (int c = tid; c < 451; c += 256) {
        float s = 0.f;
        for (int sl = 0; sl < NSLAB; ++sl)
            s += ppool[((size_t)(b * NSLAB + sl) * J_ + j) * 451 + c];
        pooled[(size_t)bj * 451 + c] = s * inv;
    }
}

extern "C" void kernel_launch(void* const* d_in, const int* in_sizes, int n_in,
                              void* d_out, int out_size, void* d_ws, size_t ws_size,
                              hipStream_t stream) {
    const float* V  = (const float*)d_in[0];
    const float* W  = (const float*)d_in[1];
    const int* ringIdx = (const int*)d_in[2];
    const float* g1w = (const float*)d_in[3];
    const float* g1b = (const float*)d_in[4];
    const float* g2w = (const float*)d_in[5];
    const float* g2b = (const float*)d_in[6];
    const float* g3w = (const float*)d_in[7];
    const float* g3b = (const float*)d_in[8];
    const float* s1w = (const float*)d_in[9];
    const float* s1b = (const float*)d_in[10];
    const float* s2w = (const float*)d_in[11];
    const float* s2b = (const float*)d_in[12];
    const float* s3w = (const float*)d_in[13];
    const float* s3b = (const float*)d_in[14];
    const float* m1w = (const float*)d_in[15];
    const float* m1b = (const float*)d_in[16];
    const float* m2w = (const float*)d_in[17];
    const float* m2b = (const float*)d_in[18];
    const float* m3w = (const float*)d_in[19];
    const float* m3b = (const float*)d_in[20];
    (void)n_in; (void)in_sizes; (void)out_size;

    const int szP1 = 3 * 128,    szP2 = 64 * 256,  szP3 = 128 * 512;
    const int szP4 = 451 * 512,  szP5 = 256 * 256, szP6 = 128 * 128;
    const int szP7 = 448 * 512,  szP8 = 512 * 256, szP9 = 256 * 3;

    // D region (floats): nd key-buffers (u16, N*N/2 floats each), must also
    // cover Y (M*512 f32) and the pooling scratch that alias it.
    auto dreg_floats = [&](int nd) -> size_t {
        size_t a = (size_t)nd * ((size_t)N_ * N_ / 2);
        size_t ymax = (size_t)B_ * N_ * 512;                       // 8.39M floats
        size_t pool = (size_t)B_ * NSLAB * J_ * 451 + (size_t)B_ * NSLAB * J_;
        size_t r = a;
        if (ymax > r) r = ymax;
        if (pool > r) r = pool;
        return r;
    };
    auto layout_bytes = [&](int nd) -> size_t {
        size_t f = 0;
        f += (size_t)B_ * N_ * 64 + (size_t)B_ * N_ * 128 + (size_t)B_ * N_ * 256;
        f += (size_t)B_ * N_;                         // xx
        f += dreg_floats(nd);                         // D/Y/pool region
        f += 2 * ((size_t)B_ * N_ * 128 / 2);         // Xhi/Xlo bf16 split buffers
        f += (size_t)B_ * N_ * KNN_;                  // knnIdx (ints)
        f += (size_t)B_ * J_ * 451 + (size_t)B_ * J_ * 448;
        f += (size_t)B_ * J_ * 512 + (size_t)B_ * J_ * 256;
        f += (size_t)(szP1 + szP2 + szP3 + szP4 + szP5 + szP6 + szP7 + szP8 + szP9);
        f += 128 + 256 + 512 + 512 + 256 + 128;
        return f * 4;
    };
    // nb = batches per dist/sel group (deterministic in ws_size -> graph-safe)
    int nb = 1;
    if (ws_size >= layout_bytes(4)) nb = 4;
    else if (ws_size >= layout_bytes(2)) nb = 2;

    // ---- workspace layout (floats) ----
    float* ws = (float*)d_ws;
    size_t off = 0;
    float* l1 = ws + off; off += (size_t)B_ * N_ * 64;
    float* l2 = ws + off; off += (size_t)B_ * N_ * 128;
    float* l3 = ws + off; off += (size_t)B_ * N_ * 256;
    float* xx = ws + off; off += (size_t)B_ * N_;
    float* D  = ws + off; off += dreg_floats(nb);        // keys / Y / pool region
    unsigned short* Dk = (unsigned short*)D;
    float* Y  = D;
    float* ppool = D;
    float* psw   = D + (size_t)B_ * NSLAB * J_ * 451;
    unsigned short* Xhi = (unsigned short*)(ws + off); off += (size_t)B_ * N_ * 128 / 2;
    unsigned short* Xlo = (unsigned short*)(ws + off); off += (size_t)B_ * N_ * 128 / 2;
    int* knnIdx = (int*)(ws + off); off += (size_t)B_ * N_ * KNN_;
    float* pooled = ws + off; off += (size_t)B_ * J_ * 451;
    float* joints = ws + off; off += (size_t)B_ * J_ * 448;
    float* h1 = ws + off; off += (size_t)B_ * J_ * 512;
    float* h2 = ws + off; off += (size_t)B_ * J_ * 256;
    float* P1 = ws + off; off += szP1;
    float* P2 = ws + off; off += szP2;
    float* P3 = ws + off; off += szP3;
    float* P4 = ws + off; off += szP4;
    float* P5 = ws + off; off += szP5;
    float* P6 = ws + off; off += szP6;
    float* P7 = ws + off; off += szP7;
    float* P8 = ws + off; off += szP8;
    float* P9 = ws + off; off += szP9;
    float* bb1 = ws + off; off += 128;
    float* bb2 = ws + off; off += 256;
    float* bb3 = ws + off; off += 512;
    float* bb4 = ws + off; off += 512;
    float* bb5 = ws + off; off += 256;
    float* bb6 = ws + off; off += 128;

    const int M = B_ * N_;   // 16384
    const int MJ = B_ * J_;  // 96
    const int NUTRI = NTILE * (NTILE + 1) / 2;   // 528 upper-tri tiles

    // ---- all weight prep in one launch ----
    k_prepall<<<dim3((szP4 + 255) / 256, 9), 256, 0, stream>>>(
        g1w, g1b, g2w, g2b, g3w, g3b, s1w, s1b, s2w, s2b, s3w, s3b,
        m1w, m2w, m3w, P1, P2, P3, P4, P5, P6, P7, P8, P9,
        bb1, bb2, bb3, bb4, bb5, bb6);

    // ======== geoNet layer 1: C=3 -> O=64 (fused dist+select) ========
    k_norm<<<(M + 255) / 256, 256, 0, stream>>>(V, xx, 3);
    k_selC3<<<dim3(N_ / 4, B_), 256, 0, stream>>>(V, xx, knnIdx);
    k_gemm<<<dim3(2, M / 64), 256, 0, stream>>>(V, 3, P1, Y, 128, M, 128, 3, bb1, 0);
    k_gathermax<<<M, 64, KNN_ * sizeof(int), stream>>>(Y, 64, N_, knnIdx, KNN_, l1, 64, 0, xx);

    // ======== layer 2: C=64 -> O=128 ========
    k_split<<<(M * 64 / 4 + 255) / 256, 256, 0, stream>>>(l1, Xhi, Xlo, M * 64 / 4);
    for (int g = 0; g < B_; g += nb) {
        k_dist<<<dim3(NUTRI, nb), 256, 0, stream>>>(Xhi, Xlo, 64, xx, Dk, g);
        k_sel<<<dim3(N_ / 4, nb), 256, 0, stream>>>(Dk, l1, 64, xx, knnIdx, g);
    }
    k_gemm<<<dim3(4, M / 64), 256, 0, stream>>>(l1, 64, P2, Y, 256, M, 256, 64, bb2, 0);
    k_gathermax<<<M, 128, KNN_ * sizeof(int), stream>>>(Y, 128, N_, knnIdx, KNN_, l2, 128, 0, xx);

    // ======== layer 3: C=128 -> O=256 ========
    k_split<<<(M * 128 / 4 + 255) / 256, 256, 0, stream>>>(l2, Xhi, Xlo, M * 128 / 4);
    for (int g = 0; g < B_; g += nb) {
        k_dist<<<dim3(NUTRI, nb), 256, 0, stream>>>(Xhi, Xlo, 128, xx, Dk, g);
        k_sel<<<dim3(N_ / 4, nb), 256, 0, stream>>>(Dk, l2, 128, xx, knnIdx, g);
    }
    k_gemm<<<dim3(8, M / 64), 256, 0, stream>>>(l2, 128, P3, Y, 512, M, 512, 128, bb3, 0);
    k_gathermax<<<M, 256, KNN_ * sizeof(int), stream>>>(Y, 256, N_, knnIdx, KNN_, l3, 256, 0, nullptr);

    // ======== pooling onto joints ========
    k_pool2<<<B_ * NSLAB, 256, 0, stream>>>(V, l1, l2, l3, W, ppool, psw);
    k_poolred<<<MJ, 256, 0, stream>>>(ppool, psw, pooled);

    // ======== skeleton convs ========
    k_sgemm<<<dim3(MJ, 2), 256, 451 * sizeof(float), stream>>>(pooled, 451, P4, Y, 512, 512, 451, bb4, 0);
    k_gathermax<<<MJ, 256, KR_ * sizeof(int), stream>>>(Y, 256, J_, ringIdx, KR_, joints, 448, 0, nullptr);

    k_sgemm<<<dim3(MJ, 1), 256, 256 * sizeof(float), stream>>>(joints, 448, P5, Y, 256, 256, 256, bb5, 0);
    k_gathermax<<<MJ, 128, KR_ * sizeof(int), stream>>>(Y, 128, J_, ringIdx, KR_, joints, 448, 256, nullptr);

    k_sgemm<<<dim3(MJ, 1), 256, 128 * sizeof(float), stream>>>(joints + 256, 448, P6, Y, 128, 128, 128, bb6, 0);
    k_gathermax<<<MJ, 64, KR_ * sizeof(int), stream>>>(Y, 64, J_, ringIdx, KR_, joints, 448, 384, nullptr);

    // ======== joint MLP ========
    k_sgemm<<<dim3(MJ, 2), 256, 448 * sizeof(float), stream>>>(joints, 448, P7, h1, 512, 512, 448, m1b, 1);
    k_sgemm<<<dim3(MJ, 1), 256, 512 * sizeof(float), stream>>>(h1, 512, P8, h2, 256, 256, 512, m2b, 1);
    k_sgemm<<<dim3(MJ, 1), 256, 256 * sizeof(float), stream>>>(h2, 256, P9, (float*)d_out, 3, 3, 256, m3b, 0);
}

// Round 16
// 839.207 us; speedup vs baseline: 1.5725x; 1.0118x over previous
//
#include <hip/hip_runtime.h>
#include <hip/hip_bf16.h>
#include <float.h>

// Problem constants (from reference setup_inputs)
#define B_   4
#define N_   4096
#define J_   24
#define KR_  4
#define KNN_ 20
#define SLOPE 0.2f
#define SLABN 64             // points per pooling slab
#define NSLAB (N_ / SLABN)   // 64
#define NTILE 32             // 128-wide tiles per dim
#define NUTRI (NTILE * (NTILE + 1) / 2)   // 528 upper-tri tiles
#define SCAPW 320            // per-wave survivor cap (exp. S ~ 30-50)
#define KSLACK 8u            // u16-key slack covering split-bf16 error

typedef __attribute__((ext_vector_type(8))) short bf16x8;
typedef __attribute__((ext_vector_type(4))) float f32x4;

// ---------- per-point squared norm ----------
__global__ void k_norm(const float* __restrict__ h, float* __restrict__ xx, int C) {
    int i = blockIdx.x * blockDim.x + threadIdx.x;
    if (i >= B_ * N_) return;
    const float* hp = h + (size_t)i * C;
    float s = 0.f;
    for (int c = 0; c < C; ++c) { float v = hp[c]; s += v * v; }
    xx[i] = s;
}

// ---------- monotone key maps ----------
__device__ __forceinline__ unsigned mapf(float f) {
    unsigned u = __float_as_uint(f);
    return (u & 0x80000000u) ? ~u : (u | 0x80000000u);
}
// top-16 bits of mapf: monotone f32 -> u16 (truncation preserves order)
__device__ __forceinline__ unsigned key16(float f) {
    return mapf(f) >> 16;
}

// ---------- split f32 -> bf16 hi + bf16 lo (both truncated; x = hi + lo + r, |r|<=2^-16|x|) ----------
__global__ void k_split(const float* __restrict__ h, unsigned short* __restrict__ hi,
                        unsigned short* __restrict__ lo, int total4) {
    int i = blockIdx.x * 256 + threadIdx.x;
    if (i >= total4) return;
    float4 v = ((const float4*)h)[i];
    ushort4 h4, l4;
    {
        unsigned u = __float_as_uint(v.x); h4.x = (unsigned short)(u >> 16);
        float r = v.x - __uint_as_float(u & 0xffff0000u); l4.x = (unsigned short)(__float_as_uint(r) >> 16);
    }
    {
        unsigned u = __float_as_uint(v.y); h4.y = (unsigned short)(u >> 16);
        float r = v.y - __uint_as_float(u & 0xffff0000u); l4.y = (unsigned short)(__float_as_uint(r) >> 16);
    }
    {
        unsigned u = __float_as_uint(v.z); h4.z = (unsigned short)(u >> 16);
        float r = v.z - __uint_as_float(u & 0xffff0000u); l4.z = (unsigned short)(__float_as_uint(r) >> 16);
    }
    {
        unsigned u = __float_as_uint(v.w); h4.w = (unsigned short)(u >> 16);
        float r = v.w - __uint_as_float(u & 0xffff0000u); l4.w = (unsigned short)(__float_as_uint(r) >> 16);
    }
    ((ushort4*)hi)[i] = h4;
    ((ushort4*)lo)[i] = l4;
}

// ---------- group swizzle for the key tile ----------
__device__ __forceinline__ int swz_(int row) {
    return ((row >> 3) & 7) ^ (((row >> 2) & 1) << 2);
}

// ---------- MFMA distance GEMM (split-bf16, 3-pass) -> u16 keys ----------
// 1-D grid with XCD-affine batch-major swizzle: HW round-robins blockIdx
// across the 8 XCDs; swz = (bid&7)*(nwg/8) + bid>>3 gives each XCD a
// contiguous LOGICAL chunk; logical order is batch-major, so each XCD hosts
// (half of) one batch's tiles -> that batch's Xhi/Xlo stays L2-resident
// instead of all 4 batches thrashing every XCD's L2 (r11 lesson).
__global__ __launch_bounds__(256) void k_dist(const unsigned short* __restrict__ Hi,
                                              const unsigned short* __restrict__ Lo,
                                              int C,
                                              const float* __restrict__ xxall,
                                              unsigned short* __restrict__ Dall, int b0) {
    __shared__ unsigned short tile[128][128];   // swizzled groups; 32 KiB
    int nwg = gridDim.x;                 // NUTRI * nb; divisible by 8
    int q8  = nwg >> 3;
    int bid = blockIdx.x;
    int swz = (bid & 7) * q8 + (bid >> 3);
    int bg  = swz / NUTRI;               // batch within group (batch-major)
    int t   = swz % NUTRI;               // linear upper-tri tile id
    int b = b0 + bg;
    const unsigned short* XH = Hi + (size_t)b * N_ * C;
    const unsigned short* XL = Lo + (size_t)b * N_ * C;
    const float* xxb = xxall + (size_t)b * N_;
    unsigned short* D = Dall + (size_t)bg * N_ * N_;

    int ti = 0;
    while (t >= NTILE - ti) { t -= NTILE - ti; ++ti; }
    int tj = ti + t;
    int row0 = ti * 128, col0 = tj * 128;
    int tid  = threadIdx.x;
    int wv   = tid >> 6, lane = tid & 63;
    int wr   = wv >> 1,  wc   = wv & 1;
    int rbase = row0 + wr * 64;
    int cbase = col0 + wc * 64;
    int lp    = lane & 15;        // point within frag
    int kgrp  = lane >> 4;        // k-group

    f32x4 acc[4][4];
#pragma unroll
    for (int i = 0; i < 4; ++i)
#pragma unroll
        for (int j = 0; j < 4; ++j) acc[i][j] = (f32x4){0.f, 0.f, 0.f, 0.f};

    for (int ks = 0; ks < C; ks += 32) {
        int kb = ks + kgrp * 8;
        bf16x8 ah[4], al[4];
#pragma unroll
        for (int fi = 0; fi < 4; ++fi) {
            size_t ro = (size_t)(rbase + fi * 16 + lp) * C + kb;
            ah[fi] = *(const bf16x8*)(XH + ro);
            al[fi] = *(const bf16x8*)(XL + ro);
        }
#pragma unroll
        for (int fj = 0; fj < 4; ++fj) {
            size_t co = (size_t)(cbase + fj * 16 + lp) * C + kb;
            bf16x8 bh = *(const bf16x8*)(XH + co);
            bf16x8 bl = *(const bf16x8*)(XL + co);
#pragma unroll
            for (int fi = 0; fi < 4; ++fi) {
                acc[fi][fj] = __builtin_amdgcn_mfma_f32_16x16x32_bf16(ah[fi], bh, acc[fi][fj], 0, 0, 0);
                acc[fi][fj] = __builtin_amdgcn_mfma_f32_16x16x32_bf16(ah[fi], bl, acc[fi][fj], 0, 0, 0);
                acc[fi][fj] = __builtin_amdgcn_mfma_f32_16x16x32_bf16(al[fi], bh, acc[fi][fj], 0, 0, 0);
            }
        }
    }

    // epilogue: d = xxr + xxc - 2*dot -> u16 key into swizzled LDS tile.
    float xxrv = xxb[rbase + lane];
    float xxcv = xxb[cbase + lane];
    int rsub = (lane >> 4) * 4;
#pragma unroll
    for (int fi = 0; fi < 4; ++fi) {
#pragma unroll
        for (int fj = 0; fj < 4; ++fj) {
            float xc = __shfl(xxcv, fj * 16 + lp, 64);
#pragma unroll
            for (int r = 0; r < 4; ++r) {
                float xr = __shfl(xxrv, fi * 16 + rsub + r, 64);
                float d = xr + xc - 2.f * acc[fi][fj][r];
                int row = wr * 64 + fi * 16 + rsub + r;
                int col = wc * 64 + fj * 16 + lp;
                tile[row][(((col >> 3) ^ swz_(row)) << 3) | (col & 7)] =
                    (unsigned short)key16(d);
            }
        }
    }
    __syncthreads();

    // normal store: 16-lane groups each write 256 B contiguous (one full row)
    {
        int r0  = tid >> 4;             // 0..15
        int grp = tid & 15;             // logical 8-u16 group
#pragma unroll
        for (int q = 0; q < 8; ++q) {
            int row = r0 + q * 16;
            *(uint4*)(D + (size_t)(row0 + row) * N_ + col0 + grp * 8) =
                *(const uint4*)&tile[row][(grp ^ swz_(row)) << 3];
        }
    }
    if (ti == tj) return;
    // mirror store: transpose gather from swizzled LDS; 16-lane groups write
    // 256 B contiguous
    {
        int c0g = tid >> 4;             // base column group 0..15
        int g   = tid & 15;             // lane within group -> row segment g*8
#pragma unroll
        for (int cq = 0; cq < 8; ++cq) {
            int c  = c0g + cq * 16;
            int cg = c >> 3, co = c & 7;
            unsigned short s[8];
#pragma unroll
            for (int q = 0; q < 8; ++q) {
                int row = g * 8 + q;
                s[q] = tile[row][((cg ^ swz_(row)) << 3) | co];
            }
            *(uint4*)(D + (size_t)(col0 + c) * N_ + row0 + g * 8) = *(const uint4*)s;
        }
    }
}

// ---------- ballot-based wave radix select (no dependent shuffle chains) ----------
// r-th smallest (1-indexed) of the 64 lanes' values, low nbits significant.
__device__ __forceinline__ unsigned radixsel_wave(unsigned val, int r, int nbits) {
    unsigned long long cand = ~0ull;
    unsigned prefix = 0;
    for (int bit = nbits - 1; bit >= 0; --bit) {
        unsigned long long z = cand & __ballot(!((val >> bit) & 1u));
        int cz = __popcll(z);
        if (cz >= r) cand = z;
        else { r -= cz; cand &= ~z; prefix |= 1u << bit; }
    }
    return prefix;
}

// Given per-lane u64 key (hi = mapf(d), lo = idx) and an active flag, return
// whether this lane is among the 20 smallest (u64 order) active keys.
__device__ __forceinline__ bool top20_round(unsigned long long key, bool active) {
    unsigned hi = (unsigned)(key >> 32);
    unsigned lo = (unsigned)key;
    unsigned long long amask = __ballot(active);
    int navail = __popcll(amask);
    if (navail <= KNN_) return active;
    int r = KNN_;
    unsigned long long cand = amask;
    unsigned prefix = 0;
    for (int bit = 31; bit >= 0; --bit) {
        unsigned long long z = cand & __ballot(!((hi >> bit) & 1u));
        int cz = __popcll(z);
        if (cz >= r) cand = z;
        else { r -= cz; cand &= ~z; prefix |= 1u << bit; }
    }
    unsigned long long c2 = __ballot(active && hi == prefix);
    unsigned p2 = 0;
    for (int bit = 11; bit >= 0; --bit) {          // idx < 4096 -> 12 bits
        unsigned long long z = c2 & __ballot(!((lo >> bit) & 1u));
        int cz = __popcll(z);
        if (cz >= r) c2 = z;
        else { r -= cz; c2 &= ~z; p2 |= 1u << bit; }
    }
    return active && (hi < prefix || (hi == prefix && lo <= p2));
}

// Per-wave exact top-20 of skey[0..S) via rounds of ballot select; winners
// ordered by all-pairs rank over 20 elements in LDS (no chains, no barriers).
__device__ __forceinline__ void final_top20(const unsigned long long* skey, int S,
                                            unsigned long long* wbuf,
                                            int lane, int* idxout, int obase) {
    unsigned long long key = (lane < S) ? skey[lane] : ~0ull;
    bool active = (lane < S);
    int consumed = (S < 64) ? S : 64;
    int nw = 0;
    for (;;) {
        bool win = top20_round(key, active);
        unsigned long long wb = __ballot(win);
        nw = __popcll(wb);
        int pos = __popcll(wb & ((1ull << lane) - 1ull));
        if (win) wbuf[pos] = key;
        if (consumed >= S) break;
        int src = consumed + lane - nw;
        key = (lane < nw) ? wbuf[lane] : ((src < S) ? skey[src] : ~0ull);
        active = (lane < nw) || (src >= consumed && src < S);
        consumed += 64 - nw;
    }
    if (lane < nw) {
        unsigned long long mine = wbuf[lane];
        int rank = 0;
        for (int i = 0; i < nw; ++i) rank += (wbuf[i] < mine);
        idxout[obase + rank] = (int)(unsigned)mine;
    }
}

// ---------- wave-autonomous top-20 from u16 key rows (XCD-affine) ----------
// One wave = one full row (64 keys/lane). Same selection proofs as before.
// 1-D grid with the same XCD-affine batch-major swizzle as k_dist so the
// f32 X rows used in the exact recompute stay L2-resident per XCD.
__global__ __launch_bounds__(256) void k_sel(const unsigned short* __restrict__ Dall,
                                             const float* __restrict__ Xall, int C,
                                             const float* __restrict__ xxall,
                                             int* __restrict__ knnIdx, int b0) {
    __shared__ unsigned short sidx[4][SCAPW];
    __shared__ unsigned long long skey[4][SCAPW];
    __shared__ unsigned long long wbuf[4][24];
    __shared__ int scnt[4];
    int nwg = gridDim.x;                 // 1024 * nb; divisible by 8
    int q8  = nwg >> 3;
    int bid = blockIdx.x;
    int swz = (bid & 7) * q8 + (bid >> 3);
    int bg  = swz >> 10;                 // batch within group (1024 blocks/batch)
    int qg  = swz & 1023;
    int b = b0 + bg;
    const unsigned short* Db = Dall + (size_t)bg * N_ * N_;
    const float* Xb  = Xall + (size_t)b * N_ * C;
    const float* xxb = xxall + (size_t)b * N_;
    int* idxout = knnIdx + (size_t)b * N_ * KNN_;
    int wv   = threadIdx.x >> 6;
    int lane = threadIdx.x & 63;
    int ql   = qg * 4 + wv;
    if (lane == 0) scnt[wv] = 0;

    const uint4* row = (const uint4*)(Db + (size_t)ql * N_);
    uint4 K[8];
#pragma unroll
    for (int q = 0; q < 8; ++q) K[q] = row[q * 64 + lane];

    // per-lane min of its 64 keys
    unsigned mn = 0xffffu;
#pragma unroll
    for (int q = 0; q < 8; ++q) {
        const unsigned* w = (const unsigned*)&K[q];
#pragma unroll
        for (int h = 0; h < 4; ++h) {
            unsigned lo = w[h] & 0xffffu, hi = w[h] >> 16;
            mn = (lo < mn) ? lo : mn;
            mn = (hi < mn) ? hi : mn;
        }
    }
    unsigned tau = radixsel_wave(mn, KNN_, 16) + KSLACK;
    if (tau > 0xffffu) tau = 0xffffu;

    // count per-lane survivors, reserve a private range with ONE wave-wide atomic
    int nl = 0;
#pragma unroll
    for (int q = 0; q < 8; ++q) {
        const unsigned* w = (const unsigned*)&K[q];
#pragma unroll
        for (int h = 0; h < 4; ++h) {
            nl += ((w[h] & 0xffffu) <= tau);
            nl += ((w[h] >> 16) <= tau);
        }
    }
    int p = atomicAdd(&scnt[wv], nl);
#pragma unroll
    for (int q = 0; q < 8; ++q) {
        const unsigned* w = (const unsigned*)&K[q];
        int jb = (q * 64 + lane) * 8;
#pragma unroll
        for (int h = 0; h < 4; ++h) {
            if ((w[h] & 0xffffu) <= tau) { if (p < SCAPW) sidx[wv][p] = (unsigned short)(jb + 2 * h);     ++p; }
            if ((w[h] >> 16)     <= tau) { if (p < SCAPW) sidx[wv][p] = (unsigned short)(jb + 2 * h + 1); ++p; }
        }
    }
    int S = scnt[wv];                 // wave-ordered LDS: atomic precedes this read
    if (S > SCAPW) S = SCAPW;

    // recompute exact f32 distances for survivors (X rows are L2-resident)
    float xxq = xxb[ql];
    const float4* xq4 = (const float4*)(Xb + (size_t)ql * C);
    for (int s = lane; s < S; s += 64) {
        int j = (int)sidx[wv][s];
        const float4* xj = (const float4*)(Xb + (size_t)j * C);
        float a0 = 0.f, a1 = 0.f, a2 = 0.f, a3 = 0.f;
        for (int c4 = 0; c4 < (C >> 2); ++c4) {
            float4 x = xj[c4]; float4 qv = xq4[c4];
            a0 = fmaf(qv.x, x.x, a0);
            a1 = fmaf(qv.y, x.y, a1);
            a2 = fmaf(qv.z, x.z, a2);
            a3 = fmaf(qv.w, x.w, a3);
        }
        float dot = (a0 + a1) + (a2 + a3);
        float d = xxq + xxb[j] - 2.f * dot;
        skey[wv][s] = ((unsigned long long)mapf(d) << 32) | (unsigned)j;
    }
    final_top20(skey[wv], S, wbuf[wv], lane, idxout, ql * KNN_);
}

// ---------- layer-1 wave-autonomous dist+select (C=3), exact f32 keys ----------
__global__ __launch_bounds__(256) void k_selC3(const float* __restrict__ V,
                                               const float* __restrict__ xx,
                                               int* __restrict__ knnIdx) {
    __shared__ unsigned long long skey[4][SCAPW];
    __shared__ unsigned long long wbuf[4][24];
    __shared__ int scnt[4];
    int b    = blockIdx.y;
    const float* Xb  = V + (size_t)b * N_ * 3;
    const float* xxb = xx + (size_t)b * N_;
    int* idxout = knnIdx + (size_t)b * N_ * KNN_;
    int wv   = threadIdx.x >> 6;
    int lane = threadIdx.x & 63;
    int q    = blockIdx.x * 4 + wv;
    if (lane == 0) scnt[wv] = 0;

    float qx = Xb[q * 3], qy = Xb[q * 3 + 1], qz = Xb[q * 3 + 2];
    float xxq = xxb[q];

    unsigned kk[64];
#pragma unroll
    for (int cq = 0; cq < 4; ++cq) {
        int jb = (cq * 64 + lane) * 16;
        float pts[48];
        const float4* src = (const float4*)(Xb + (size_t)jb * 3);
#pragma unroll
        for (int t = 0; t < 12; ++t) ((float4*)pts)[t] = src[t];
#pragma unroll
        for (int t = 0; t < 16; ++t) {
            float dot = qx * pts[3 * t];
            dot = fmaf(qy, pts[3 * t + 1], dot);
            dot = fmaf(qz, pts[3 * t + 2], dot);
            float d = xxq + xxb[jb + t] - 2.f * dot;
            kk[cq * 16 + t] = mapf(d);
        }
    }

    unsigned mn = kk[0];
#pragma unroll
    for (int t = 1; t < 64; ++t) mn = (kk[t] < mn) ? kk[t] : mn;
    unsigned tau = radixsel_wave(mn, KNN_, 32);   // exact keys: no slack needed

    int nl = 0;
#pragma unroll
    for (int t = 0; t < 64; ++t) nl += (kk[t] <= tau);
    int p = atomicAdd(&scnt[wv], nl);
#pragma unroll
    for (int cq = 0; cq < 4; ++cq) {
        int jb = (cq * 64 + lane) * 16;
#pragma unroll
        for (int t = 0; t < 16; ++t) {
            if (kk[cq * 16 + t] <= tau) {
                if (p < SCAPW)
                    skey[wv][p] = ((unsigned long long)kk[cq * 16 + t] << 32) | (unsigned)(jb + t);
                ++p;
            }
        }
    }
    int S = scnt[wv];
    if (S > SCAPW) S = SCAPW;
    final_top20(skey[wv], S, wbuf[wv], lane, idxout, q * KNN_);
}

// ---------- fused weight prep ----------
__device__ __forceinline__ void prepP_elem(const float* __restrict__ w,
                                           const float* __restrict__ bias,
                                           int C, int O, float* __restrict__ P,
                                           float* __restrict__ b2, int i) {
    int O2 = 2 * O;
    if (i < O2) b2[i] = (i < O) ? 0.f : bias[i - O];
    if (i >= C * O2) return;
    int k = i / O2, col = i % O2;
    float v;
    if (col < O) v = w[(size_t)col * 2 * C + k];
    else { int o = col - O; v = w[(size_t)o * 2 * C + C + k] - w[(size_t)o * 2 * C + k]; }
    P[i] = v;
}
__device__ __forceinline__ void transp_elem(const float* __restrict__ w, int O, int K,
                                            float* __restrict__ wT, int i) {
    if (i >= O * K) return;
    int k = i / O, o = i % O;
    wT[i] = w[(size_t)o * K + k];
}

__global__ void k_prepall(const float* g1w, const float* g1b,
                          const float* g2w, const float* g2b,
                          const float* g3w, const float* g3b,
                          const float* s1w, const float* s1b,
                          const float* s2w, const float* s2b,
                          const float* s3w, const float* s3b,
                          const float* m1w, const float* m2w, const float* m3w,
                          float* P1, float* P2, float* P3, float* P4, float* P5,
                          float* P6, float* P7, float* P8, float* P9,
                          float* bb1, float* bb2, float* bb3,
                          float* bb4, float* bb5, float* bb6) {
    int i = blockIdx.x * 256 + threadIdx.x;
    switch (blockIdx.y) {
        case 0: prepP_elem(g1w, g1b, 3,   64,  P1, bb1, i); break;
        case 1: prepP_elem(g2w, g2b, 64,  128, P2, bb2, i); break;
        case 2: prepP_elem(g3w, g3b, 128, 256, P3, bb3, i); break;
        case 3: prepP_elem(s1w, s1b, 451, 256, P4, bb4, i); break;
        case 4: prepP_elem(s2w, s2b, 256, 128, P5, bb5, i); break;
        case 5: prepP_elem(s3w, s3b, 128, 64,  P6, bb6, i); break;
        case 6: transp_elem(m1w, 512, 448, P7, i); break;
        case 7: transp_elem(m2w, 256, 512, P8, i); break;
        case 8: transp_elem(m3w, 3,   256, P9, i); break;
    }
}

// ---------- tiled f32 GEMM (large M) ----------
__global__ __launch_bounds__(256) void k_gemm(const float* __restrict__ A, int lda,
                                              const float* __restrict__ Bm,
                                              float* __restrict__ Cm, int ldc,
                                              int M, int N, int K,
                                              const float* __restrict__ bias, int leaky) {
    __shared__ float As[16][68];
    __shared__ float Bs[16][68];
    int tid = threadIdx.x;
    int row0 = blockIdx.y * 64, col0 = blockIdx.x * 64;
    int tr = tid >> 4, tc = tid & 15;
    float acc[4][4] = {{0.f}};
    for (int kt = 0; kt < K; kt += 16) {
#pragma unroll
        for (int i = 0; i < 4; ++i) {
            int e = tid + 256 * i;
            int r = e >> 4, kk = e & 15;
            int gr = row0 + r, gk = kt + kk;
            float v = 0.f;
            if (gr < M && gk < K) v = A[(size_t)gr * lda + gk];
            As[kk][r] = v;
        }
#pragma unroll
        for (int i = 0; i < 4; ++i) {
            int e = tid + 256 * i;
            int kk = e >> 6, c = e & 63;
            int gk = kt + kk, gc = col0 + c;
            float v = 0.f;
            if (gk < K && gc < N) v = Bm[(size_t)gk * N + gc];
            Bs[kk][c] = v;
        }
        __syncthreads();
#pragma unroll
        for (int kk = 0; kk < 16; ++kk) {
            float a[4], bv[4];
            *(float4*)&a[0]  = *(const float4*)&As[kk][tr * 4];
            *(float4*)&bv[0] = *(const float4*)&Bs[kk][tc * 4];
#pragma unroll
            for (int i = 0; i < 4; ++i)
#pragma unroll
                for (int j = 0; j < 4; ++j) acc[i][j] += a[i] * bv[j];
        }
        __syncthreads();
    }
#pragma unroll
    for (int i = 0; i < 4; ++i) {
        int r = row0 + tr * 4 + i;
        if (r >= M) continue;
#pragma unroll
        for (int j = 0; j < 4; ++j) {
            int c = col0 + tc * 4 + j;
            if (c >= N) continue;
            float v = acc[i][j];
            if (bias) v += bias[c];
            if (leaky) v = v >= 0.f ? v : SLOPE * v;
            Cm[(size_t)r * ldc + c] = v;
        }
    }
}

// ---------- small-M GEMM ----------
__global__ __launch_bounds__(256) void k_sgemm(const float* __restrict__ A, int lda,
                                               const float* __restrict__ Bm,
                                               float* __restrict__ Cm, int ldc,
                                               int N, int K,
                                               const float* __restrict__ bias, int leaky) {
    extern __shared__ float Arow[];
    int r   = blockIdx.x;
    int c0  = blockIdx.y * 256;
    int tid = threadIdx.x;
    for (int k = tid; k < K; k += 256) Arow[k] = A[(size_t)r * lda + k];
    __syncthreads();
    int c = c0 + tid;
    if (c >= N) return;
    float acc = bias ? bias[c] : 0.f;
    for (int k = 0; k < K; ++k) acc += Arow[k] * Bm[(size_t)k * N + c];
    if (leaky) acc = acc >= 0.f ? acc : SLOPE * acc;
    Cm[(size_t)r * ldc + c] = acc;
}

// ---------- gather-max epilogue (+ optional fused row-norm) ----------
__global__ void k_gathermax(const float* __restrict__ Y, int O, int R,
                            const int* __restrict__ idx, int kc,
                            float* __restrict__ out, int ldo, int ooff,
                            float* __restrict__ xxout) {
    extern __shared__ int sidx[];
    __shared__ float red[256];
    int br = blockIdx.x;
    int b  = br / R;
    int o  = threadIdx.x;
    if (o < kc) sidx[o] = idx[(size_t)br * kc + o];
    __syncthreads();
    int O2 = 2 * O;
    float z = Y[(size_t)br * O2 + O + o];
    float best = -FLT_MAX;
    for (int k = 0; k < kc; ++k) {
        int m = sidx[k];
        best = fmaxf(best, Y[(size_t)(b * R + m) * O2 + o]);
    }
    float r = z + best;
    r = r >= 0.f ? r : SLOPE * r;
    out[(size_t)br * ldo + ooff + o] = r;
    if (xxout) {
        red[o] = r * r;
        __syncthreads();
        for (int s = blockDim.x >> 1; s > 0; s >>= 1) {
            if (o < s) red[o] += red[o + s];
            __syncthreads();
        }
        if (o == 0) xxout[br] = red[0];
    }
}

// ---------- channel map ----------
__device__ __forceinline__ void chan_map(int b, int c,
                                         const float* Vf, const float* l1,
                                         const float* l2, const float* l3,
                                         const float*& p, int& st) {
    if (c < 3)        { st = 3;   p = Vf + (size_t)b * N_ * 3   + c; }
    else if (c < 67)  { st = 64;  p = l1 + (size_t)b * N_ * 64  + (c - 3); }
    else if (c < 195) { st = 128; p = l2 + (size_t)b * N_ * 128 + (c - 67); }
    else              { st = 256; p = l3 + (size_t)b * N_ * 256 + (c - 195); }
}

// ---------- pooling phase 1 ----------
__global__ __launch_bounds__(256) void k_pool2(const float* __restrict__ Vf,
                                               const float* __restrict__ l1,
                                               const float* __restrict__ l2,
                                               const float* __restrict__ l3,
                                               const float* __restrict__ W,
                                               float* __restrict__ ppool,
                                               float* __restrict__ psw) {
    __shared__ float Wl[SLABN][J_];
    int blk  = blockIdx.x;
    int b    = blk / NSLAB, slab = blk % NSLAB;
    int n0   = slab * SLABN;
    int tid  = threadIdx.x;

    for (int e = tid; e < J_ * SLABN; e += 256) {
        int j = e / SLABN, n = e % SLABN;
        Wl[n][j] = W[((size_t)b * J_ + j) * N_ + n0 + n];
    }
    __syncthreads();

    if (tid < J_) {
        float s = 0.f;
        for (int n = 0; n < SLABN; ++n) s += Wl[n][tid];
        psw[(size_t)blk * J_ + tid] = s;
    }

    int c0 = tid, c1 = tid + 256;
    const float *p0, *p1 = nullptr; int s0, s1 = 0;
    chan_map(b, c0, Vf, l1, l2, l3, p0, s0);
    bool has1 = (c1 < 451);
    if (has1) chan_map(b, c1, Vf, l1, l2, l3, p1, s1);

    float acc0[J_], acc1[J_];
#pragma unroll
    for (int j = 0; j < J_; ++j) { acc0[j] = 0.f; acc1[j] = 0.f; }

    for (int n = 0; n < SLABN; ++n) {
        float v0 = p0[(size_t)(n0 + n) * s0];
        float v1 = has1 ? p1[(size_t)(n0 + n) * s1] : 0.f;
        const float* wn = &Wl[n][0];
#pragma unroll
        for (int q = 0; q < J_ / 4; ++q) {
            float4 w4 = *(const float4*)(wn + 4 * q);
            acc0[4*q+0] += w4.x * v0;  acc1[4*q+0] += w4.x * v1;
            acc0[4*q+1] += w4.y * v0;  acc1[4*q+1] += w4.y * v1;
            acc0[4*q+2] += w4.z * v0;  acc1[4*q+2] += w4.z * v1;
            acc0[4*q+3] += w4.w * v0;  acc1[4*q+3] += w4.w * v1;
        }
    }
    float* pp = ppool + (size_t)blk * J_ * 451;
#pragma unroll
    for (int j = 0; j < J_; ++j) {
        pp[(size_t)j * 451 + c0] = acc0[j];
        if (has1) pp[(size_t)j * 451 + c1] = acc1[j];
    }
}

// ---------- pooling phase 2 ----------
__global__ __launch_bounds__(256) void k_poolred(const float* __restrict__ ppool,
                                                 const float* __restrict__ psw,
                                                 float* __restrict__ pooled) {
    int bj = blockIdx.x;
    int b  = bj / J_, j = bj % J_;
    int tid = threadIdx.x;

    float sw = 0.f;
    for (int sl = 0; sl < NSLAB; ++sl) sw += psw[(size_t)(b * NSLAB + sl) * J_ + j];
    float inv = 1.f / (sw + 1e-5f);

    for (int c = tid; c < 451; c += 256) {
        float s = 0.f;
        for (int sl = 0; sl < NSLAB; ++sl)
            s += ppool[((size_t)(b * NSLAB + sl) * J_ + j) * 451 + c];
        pooled[(size_t)bj * 451 + c] = s * inv;
    }
}

extern "C" void kernel_launch(void* const* d_in, const int* in_sizes, int n_in,
                              void* d_out, int out_size, void* d_ws, size_t ws_size,
                              hipStream_t stream) {
    const float* V  = (const float*)d_in[0];
    const float* W  = (const float*)d_in[1];
    const int* ringIdx = (const int*)d_in[2];
    const float* g1w = (const float*)d_in[3];
    const float* g1b = (const float*)d_in[4];
    const float* g2w = (const float*)d_in[5];
    const float* g2b = (const float*)d_in[6];
    const float* g3w = (const float*)d_in[7];
    const float* g3b = (const float*)d_in[8];
    const float* s1w = (const float*)d_in[9];
    const float* s1b = (const float*)d_in[10];
    const float* s2w = (const float*)d_in[11];
    const float* s2b = (const float*)d_in[12];
    const float* s3w = (const float*)d_in[13];
    const float* s3b = (const float*)d_in[14];
    const float* m1w = (const float*)d_in[15];
    const float* m1b = (const float*)d_in[16];
    const float* m2w = (const float*)d_in[17];
    const float* m2b = (const float*)d_in[18];
    const float* m3w = (const float*)d_in[19];
    const float* m3b = (const float*)d_in[20];
    (void)n_in; (void)in_sizes; (void)out_size;

    const int szP1 = 3 * 128,    szP2 = 64 * 256,  szP3 = 128 * 512;
    const int szP4 = 451 * 512,  szP5 = 256 * 256, szP6 = 128 * 128;
    const int szP7 = 448 * 512,  szP8 = 512 * 256, szP9 = 256 * 3;

    // D region (floats): nd key-buffers (u16, N*N/2 floats each), must also
    // cover Y (M*512 f32) and the pooling scratch that alias it.
    auto dreg_floats = [&](int nd) -> size_t {
        size_t a = (size_t)nd * ((size_t)N_ * N_ / 2);
        size_t ymax = (size_t)B_ * N_ * 512;                       // 8.39M floats
        size_t pool = (size_t)B_ * NSLAB * J_ * 451 + (size_t)B_ * NSLAB * J_;
        size_t r = a;
        if (ymax > r) r = ymax;
        if (pool > r) r = pool;
        return r;
    };
    auto layout_bytes = [&](int nd) -> size_t {
        size_t f = 0;
        f += (size_t)B_ * N_ * 64 + (size_t)B_ * N_ * 128 + (size_t)B_ * N_ * 256;
        f += (size_t)B_ * N_;                         // xx
        f += dreg_floats(nd);                         // D/Y/pool region
        f += 2 * ((size_t)B_ * N_ * 128 / 2);         // Xhi/Xlo bf16 split buffers
        f += (size_t)B_ * N_ * KNN_;                  // knnIdx (ints)
        f += (size_t)B_ * J_ * 451 + (size_t)B_ * J_ * 448;
        f += (size_t)B_ * J_ * 512 + (size_t)B_ * J_ * 256;
        f += (size_t)(szP1 + szP2 + szP3 + szP4 + szP5 + szP6 + szP7 + szP8 + szP9);
        f += 128 + 256 + 512 + 512 + 256 + 128;
        return f * 4;
    };
    // nb = batches per dist/sel group (deterministic in ws_size -> graph-safe)
    int nb = 1;
    if (ws_size >= layout_bytes(4)) nb = 4;
    else if (ws_size >= layout_bytes(2)) nb = 2;

    // ---- workspace layout (floats) ----
    float* ws = (float*)d_ws;
    size_t off = 0;
    float* l1 = ws + off; off += (size_t)B_ * N_ * 64;
    float* l2 = ws + off; off += (size_t)B_ * N_ * 128;
    float* l3 = ws + off; off += (size_t)B_ * N_ * 256;
    float* xx = ws + off; off += (size_t)B_ * N_;
    float* D  = ws + off; off += dreg_floats(nb);        // keys / Y / pool region
    unsigned short* Dk = (unsigned short*)D;
    float* Y  = D;
    float* ppool = D;
    float* psw   = D + (size_t)B_ * NSLAB * J_ * 451;
    unsigned short* Xhi = (unsigned short*)(ws + off); off += (size_t)B_ * N_ * 128 / 2;
    unsigned short* Xlo = (unsigned short*)(ws + off); off += (size_t)B_ * N_ * 128 / 2;
    int* knnIdx = (int*)(ws + off); off += (size_t)B_ * N_ * KNN_;
    float* pooled = ws + off; off += (size_t)B_ * J_ * 451;
    float* joints = ws + off; off += (size_t)B_ * J_ * 448;
    float* h1 = ws + off; off += (size_t)B_ * J_ * 512;
    float* h2 = ws + off; off += (size_t)B_ * J_ * 256;
    float* P1 = ws + off; off += szP1;
    float* P2 = ws + off; off += szP2;
    float* P3 = ws + off; off += szP3;
    float* P4 = ws + off; off += szP4;
    float* P5 = ws + off; off += szP5;
    float* P6 = ws + off; off += szP6;
    float* P7 = ws + off; off += szP7;
    float* P8 = ws + off; off += szP8;
    float* P9 = ws + off; off += szP9;
    float* bb1 = ws + off; off += 128;
    float* bb2 = ws + off; off += 256;
    float* bb3 = ws + off; off += 512;
    float* bb4 = ws + off; off += 512;
    float* bb5 = ws + off; off += 256;
    float* bb6 = ws + off; off += 128;

    const int M = B_ * N_;   // 16384
    const int MJ = B_ * J_;  // 96

    // ---- all weight prep in one launch ----
    k_prepall<<<dim3((szP4 + 255) / 256, 9), 256, 0, stream>>>(
        g1w, g1b, g2w, g2b, g3w, g3b, s1w, s1b, s2w, s2b, s3w, s3b,
        m1w, m2w, m3w, P1, P2, P3, P4, P5, P6, P7, P8, P9,
        bb1, bb2, bb3, bb4, bb5, bb6);

    // ======== geoNet layer 1: C=3 -> O=64 (fused dist+select) ========
    k_norm<<<(M + 255) / 256, 256, 0, stream>>>(V, xx, 3);
    k_selC3<<<dim3(N_ / 4, B_), 256, 0, stream>>>(V, xx, knnIdx);
    k_gemm<<<dim3(2, M / 64), 256, 0, stream>>>(V, 3, P1, Y, 128, M, 128, 3, bb1, 0);
    k_gathermax<<<M, 64, KNN_ * sizeof(int), stream>>>(Y, 64, N_, knnIdx, KNN_, l1, 64, 0, xx);

    // ======== layer 2: C=64 -> O=128 ========
    k_split<<<(M * 64 / 4 + 255) / 256, 256, 0, stream>>>(l1, Xhi, Xlo, M * 64 / 4);
    for (int g = 0; g < B_; g += nb) {
        k_dist<<<dim3(NUTRI * nb), 256, 0, stream>>>(Xhi, Xlo, 64, xx, Dk, g);
        k_sel<<<dim3((N_ / 4) * nb), 256, 0, stream>>>(Dk, l1, 64, xx, knnIdx, g);
    }
    k_gemm<<<dim3(4, M / 64), 256, 0, stream>>>(l1, 64, P2, Y, 256, M, 256, 64, bb2, 0);
    k_gathermax<<<M, 128, KNN_ * sizeof(int), stream>>>(Y, 128, N_, knnIdx, KNN_, l2, 128, 0, xx);

    // ======== layer 3: C=128 -> O=256 ========
    k_split<<<(M * 128 / 4 + 255) / 256, 256, 0, stream>>>(l2, Xhi, Xlo, M * 128 / 4);
    for (int g = 0; g < B_; g += nb) {
        k_dist<<<dim3(NUTRI * nb), 256, 0, stream>>>(Xhi, Xlo, 128, xx, Dk, g);
        k_sel<<<dim3((N_ / 4) * nb), 256, 0, stream>>>(Dk, l2, 128, xx, knnIdx, g);
    }
    k_gemm<<<dim3(8, M / 64), 256, 0, stream>>>(l2, 128, P3, Y, 512, M, 512, 128, bb3, 0);
    k_gathermax<<<M, 256, KNN_ * sizeof(int), stream>>>(Y, 256, N_, knnIdx, KNN_, l3, 256, 0, nullptr);

    // ======== pooling onto joints ========
    k_pool2<<<B_ * NSLAB, 256, 0, stream>>>(V, l1, l2, l3, W, ppool, psw);
    k_poolred<<<MJ, 256, 0, stream>>>(ppool, psw, pooled);

    // ======== skeleton convs ========
    k_sgemm<<<dim3(MJ, 2), 256, 451 * sizeof(float), stream>>>(pooled, 451, P4, Y, 512, 512, 451, bb4, 0);
    k_gathermax<<<MJ, 256, KR_ * sizeof(int), stream>>>(Y, 256, J_, ringIdx, KR_, joints, 448, 0, nullptr);

    k_sgemm<<<dim3(MJ, 1), 256, 256 * sizeof(float), stream>>>(joints, 448, P5, Y, 256, 256, 256, bb5, 0);
    k_gathermax<<<MJ, 128, KR_ * sizeof(int), stream>>>(Y, 128, J_, ringIdx, KR_, joints, 448, 256, nullptr);

    k_sgemm<<<dim3(MJ, 1), 256, 128 * sizeof(float), stream>>>(joints + 256, 448, P6, Y, 128, 128, 128, bb6, 0);
    k_gathermax<<<MJ, 64, KR_ * sizeof(int), stream>>>(Y, 64, J_, ringIdx, KR_, joints, 448, 384, nullptr);

    // ======== joint MLP ========
    k_sgemm<<<dim3(MJ, 2), 256, 448 * sizeof(float), stream>>>(joints, 448, P7, h1, 512, 512, 448, m1b, 1);
    k_sgemm<<<dim3(MJ, 1), 256, 512 * sizeof(float), stream>>>(h1, 512, P8, h2, 256, 256, 512, m2b, 1);
    k_sgemm<<<dim3(MJ, 1), 256, 256 * sizeof(float), stream>>>(h2, 256, P9, (float*)d_out, 3, 3, 256, m3b, 0);
}